// Round 3
// baseline (4917.023 us; speedup 1.0000x reference)
//
#include <hip/hip_runtime.h>
#include <hip/hip_bf16.h>
#include <cstdint>

#define HFEAT 128
#define CIN   256

// ---------------- CSR build ----------------

__global__ void k_zero_i32(int* __restrict__ p, int n){
  int i = blockIdx.x*blockDim.x + threadIdx.x;
  if (i < n) p[i] = 0;
}

__global__ void k_count(const int* __restrict__ dst, int E, int* __restrict__ counts){
  int e = blockIdx.x*blockDim.x + threadIdx.x;
  if (e < E) atomicAdd(&counts[dst[e]], 1);
}

__global__ void k_dinv(const int* __restrict__ counts, int n, float* __restrict__ dinv){
  int i = blockIdx.x*blockDim.x + threadIdx.x;
  if (i < n) dinv[i] = rsqrtf((float)counts[i] + 1.0f);
}

__global__ void k_scan1(const int* __restrict__ counts, int n,
                        int* __restrict__ excl, int* __restrict__ bsum){
  __shared__ int sm[1024];
  int t = threadIdx.x;
  int i = blockIdx.x*1024 + t;
  int v = (i < n) ? counts[i] : 0;
  sm[t] = v;
  __syncthreads();
  for (int off = 1; off < 1024; off <<= 1){
    int add = (t >= off) ? sm[t-off] : 0;
    __syncthreads();
    sm[t] += add;
    __syncthreads();
  }
  if (i < n) excl[i] = sm[t] - v;
  if (t == 1023) bsum[blockIdx.x] = sm[t];
}

__global__ void k_scan2(int* __restrict__ bsum, int nb){
  if (threadIdx.x == 0 && blockIdx.x == 0){
    int run = 0;
    for (int b = 0; b < nb; b++){ int v = bsum[b]; bsum[b] = run; run += v; }
  }
}

__global__ void k_scan3(const int* __restrict__ bsum, int n, int E,
                        int* __restrict__ rowoff, int* __restrict__ cursor){
  int i = blockIdx.x*blockDim.x + threadIdx.x;   // blockDim == 1024
  if (i < n){
    int v = rowoff[i] + bsum[blockIdx.x];
    rowoff[i] = v;
    cursor[i] = v;
  }
  if (i == 0) rowoff[n] = E;
}

__global__ void k_fill(const int* __restrict__ src, const int* __restrict__ dst, int E,
                       const float* __restrict__ dinv, int* __restrict__ cursor,
                       int2* __restrict__ csr){
  int e = blockIdx.x*blockDim.x + threadIdx.x;
  if (e < E){
    int s = src[e], d = dst[e];
    int pos = atomicAdd(&cursor[d], 1);
    csr[pos] = make_int2(s, __float_as_int(dinv[s]*dinv[d]));
  }
}

// ---------------- Tiled GEMM (fp32 vector ALU, LDS-staged) ----------------
// C[64 x 128] tile per 256-thread block; thread computes 4 rows x 8 cols.
// K-tiles of 32; x-tile [64][36] (pad kills bank conflicts), W-tile [32][32] float4.
// Next tile prefetched to registers before compute (hides L2 latency).

template<int K, bool BIAS>
__global__ void __launch_bounds__(256, 4) k_gemm(const float* __restrict__ A,
                                                 const float* __restrict__ Wa,
                                                 const float* __restrict__ Wb,
                                                 const float* __restrict__ ba,
                                                 const float* __restrict__ bb,
                                                 float* __restrict__ Ca,
                                                 float* __restrict__ Cb,
                                                 int n){
  __shared__ float  lds_x[64][36];
  __shared__ float4 lds_w[32][32];

  const float* W    = (blockIdx.y == 0) ? Wa : Wb;
  const float* bias = (blockIdx.y == 0) ? ba : bb;
  float*       C    = (blockIdx.y == 0) ? Ca : Cb;

  const int tid  = threadIdx.x;
  const int cg   = tid & 15;          // col group -> c0 = cg*8
  const int rg   = tid >> 4;          // row group -> r0 = rg*4
  const int row0 = blockIdx.x * 64;
  const int c0   = cg * 8;
  const int r0   = rg * 4;

  // staging maps (coalesced: consecutive lanes -> consecutive float4)
  const int xrow0 = tid >> 3;         // rows 0..31 (j=0), +32 (j=1)
  const int xkq   = tid & 7;          // float4 index within 32-wide k chunk
  const int wr0   = tid >> 5;         // W rows 0..7 (+8j)
  const int wcw   = tid & 31;         // float4 col index

  int xra = row0 + xrow0;        if (xra >= n) xra = n - 1;
  int xrb = row0 + xrow0 + 32;   if (xrb >= n) xrb = n - 1;
  const float* Axa = A + (size_t)xra * K + xkq * 4;
  const float* Axb = A + (size_t)xrb * K + xkq * 4;
  const float* Wp  = W + (size_t)wr0 * HFEAT + wcw * 4;

  float acc[4][8];
  #pragma unroll
  for (int i = 0; i < 4; i++)
    #pragma unroll
    for (int j = 0; j < 8; j++) acc[i][j] = 0.f;

  const int NT = K / 32;
  float4 px0, px1, pw0, pw1, pw2, pw3;

  // prologue: load tile 0
  px0 = *(const float4*)(Axa);
  px1 = *(const float4*)(Axb);
  pw0 = *(const float4*)(Wp);
  pw1 = *(const float4*)(Wp +  8 * HFEAT);
  pw2 = *(const float4*)(Wp + 16 * HFEAT);
  pw3 = *(const float4*)(Wp + 24 * HFEAT);

  #pragma unroll
  for (int t = 0; t < NT; ++t){
    // write staged regs to LDS
    *(float4*)&lds_x[xrow0     ][xkq * 4] = px0;
    *(float4*)&lds_x[xrow0 + 32][xkq * 4] = px1;
    lds_w[wr0     ][wcw] = pw0;
    lds_w[wr0 +  8][wcw] = pw1;
    lds_w[wr0 + 16][wcw] = pw2;
    lds_w[wr0 + 24][wcw] = pw3;
    __syncthreads();

    // prefetch next tile into regs (global latency hidden under compute)
    if (t + 1 < NT){
      int kt = (t + 1) * 32;
      px0 = *(const float4*)(Axa + kt);
      px1 = *(const float4*)(Axb + kt);
      pw0 = *(const float4*)(Wp + (size_t)kt * HFEAT);
      pw1 = *(const float4*)(Wp + (size_t)(kt +  8) * HFEAT);
      pw2 = *(const float4*)(Wp + (size_t)(kt + 16) * HFEAT);
      pw3 = *(const float4*)(Wp + (size_t)(kt + 24) * HFEAT);
    }

    // compute on current tile
    #pragma unroll
    for (int k4 = 0; k4 < 8; ++k4){
      const int k = k4 * 4;
      float4 xv[4];
      #pragma unroll
      for (int i = 0; i < 4; i++) xv[i] = *(const float4*)&lds_x[r0 + i][k];
      #pragma unroll
      for (int kk = 0; kk < 4; kk++){
        float4 w0 = lds_w[k + kk][cg * 2];
        float4 w1 = lds_w[k + kk][cg * 2 + 1];
        #pragma unroll
        for (int i = 0; i < 4; i++){
          float xs = (kk == 0) ? xv[i].x : (kk == 1) ? xv[i].y : (kk == 2) ? xv[i].z : xv[i].w;
          acc[i][0] = fmaf(xs, w0.x, acc[i][0]);
          acc[i][1] = fmaf(xs, w0.y, acc[i][1]);
          acc[i][2] = fmaf(xs, w0.z, acc[i][2]);
          acc[i][3] = fmaf(xs, w0.w, acc[i][3]);
          acc[i][4] = fmaf(xs, w1.x, acc[i][4]);
          acc[i][5] = fmaf(xs, w1.y, acc[i][5]);
          acc[i][6] = fmaf(xs, w1.z, acc[i][6]);
          acc[i][7] = fmaf(xs, w1.w, acc[i][7]);
        }
      }
    }
    __syncthreads();   // LDS safe to overwrite next iteration
  }

  float4 bv0 = make_float4(0,0,0,0), bv1 = make_float4(0,0,0,0);
  if (BIAS){
    bv0 = *(const float4*)&bias[c0];
    bv1 = *(const float4*)&bias[c0 + 4];
  }
  #pragma unroll
  for (int i = 0; i < 4; i++){
    int r = row0 + r0 + i;
    if (r < n){
      float4 o0 = make_float4(acc[i][0] + bv0.x, acc[i][1] + bv0.y,
                              acc[i][2] + bv0.z, acc[i][3] + bv0.w);
      float4 o1 = make_float4(acc[i][4] + bv1.x, acc[i][5] + bv1.y,
                              acc[i][6] + bv1.z, acc[i][7] + bv1.w);
      *(float4*)&C[(size_t)r * HFEAT + c0]     = o0;
      *(float4*)&C[(size_t)r * HFEAT + c0 + 4] = o1;
    }
  }
}

// ---------------- Aggregation: out = A_norm @ in (one wave per node) ----------------

template<int RELU>
__global__ void __launch_bounds__(256) k_agg(const float* __restrict__ in,
                                             const float* __restrict__ bias,
                                             const int* __restrict__ rowoff,
                                             const int2* __restrict__ csr,
                                             const float* __restrict__ dinv,
                                             float* __restrict__ out, int n){
  int gid = blockIdx.x*blockDim.x + threadIdx.x;
  int node = gid >> 6;
  int lane = gid & 63;
  if (node >= n) return;
  float di = dinv[node];
  float sw = di * di;
  int f0 = lane * 2;
  float2 sv = *(const float2*)(in + (size_t)node * HFEAT + f0);
  float ax = sv.x * sw, ay = sv.y * sw;
  int e = rowoff[node], e1 = rowoff[node+1];
  for (; e + 2 <= e1; e += 2){
    int2 c0 = csr[e], c1 = csr[e+1];
    float w0 = __int_as_float(c0.y), w1 = __int_as_float(c1.y);
    float2 v0 = *(const float2*)(in + (size_t)c0.x * HFEAT + f0);
    float2 v1 = *(const float2*)(in + (size_t)c1.x * HFEAT + f0);
    ax = fmaf(v0.x, w0, ax); ay = fmaf(v0.y, w0, ay);
    ax = fmaf(v1.x, w1, ax); ay = fmaf(v1.y, w1, ay);
  }
  if (e < e1){
    int2 c0 = csr[e];
    float w0 = __int_as_float(c0.y);
    float2 v0 = *(const float2*)(in + (size_t)c0.x * HFEAT + f0);
    ax = fmaf(v0.x, w0, ax); ay = fmaf(v0.y, w0, ay);
  }
  if (RELU){
    ax = fmaxf(ax + bias[f0],   0.f);
    ay = fmaxf(ay + bias[f0+1], 0.f);
  }
  *(float2*)(out + (size_t)node * HFEAT + f0) = make_float2(ax, ay);
}

// ---------------- launch ----------------

extern "C" void kernel_launch(void* const* d_in, const int* in_sizes, int n_in,
                              void* d_out, int out_size, void* d_ws, size_t ws_size,
                              hipStream_t stream){
  const float* x   = (const float*)d_in[0];
  const int*   ei  = (const int*)  d_in[1];
  const float* W1  = (const float*)d_in[2];
  const float* b1  = (const float*)d_in[3];
  const float* Wmu = (const float*)d_in[4];
  const float* bmu = (const float*)d_in[5];
  const float* Wls = (const float*)d_in[6];
  const float* bls = (const float*)d_in[7];
  int N = in_sizes[0] / CIN;
  int E = in_sizes[1] / 2;
  const int* src = ei;
  const int* dst = ei + E;
  float* out = (float*)d_out;

  char* w = (char*)d_ws;
  auto alloc = [&](size_t bytes)->char*{
    char* p = w; w += (bytes + 255) & ~(size_t)255; return p;
  };
  float* hW1   = (float*)alloc((size_t)N*HFEAT*4);   // later reused as g
  float* h     = (float*)alloc((size_t)N*HFEAT*4);
  int*   counts= (int*)  alloc((size_t)N*4);
  float* dinv  = (float*)alloc((size_t)N*4);
  int*   rowoff= (int*)  alloc(((size_t)N+1)*4);
  int*   cursor= (int*)  alloc((size_t)N*4);
  int*   bsum  = (int*)  alloc(256*4);
  int2*  csr   = (int2*) alloc((size_t)E*8);

  int nbN  = (N + 255) / 256;
  int nbE  = (E + 255) / 256;
  int nbS  = (N + 1023) / 1024;
  int nbG  = (N + 63) / 64;

  k_zero_i32<<<nbN, 256, 0, stream>>>(counts, N);
  k_count   <<<nbE, 256, 0, stream>>>(dst, E, counts);
  k_dinv    <<<nbN, 256, 0, stream>>>(counts, N, dinv);
  k_scan1   <<<nbS, 1024, 0, stream>>>(counts, N, rowoff, bsum);
  k_scan2   <<<1, 64, 0, stream>>>(bsum, nbS);
  k_scan3   <<<nbS, 1024, 0, stream>>>(bsum, N, E, rowoff, cursor);
  k_fill    <<<nbE, 256, 0, stream>>>(src, dst, E, dinv, cursor, csr);

  k_gemm<CIN, false><<<dim3(nbG, 1), 256, 0, stream>>>(x, W1, W1, nullptr, nullptr, hW1, hW1, N);
  int aggBlocks = (int)(((size_t)N*64 + 255) / 256);
  k_agg<1><<<aggBlocks, 256, 0, stream>>>(hW1, b1, rowoff, csr, dinv, h, N);
  float* g = hW1;  // hW1 dead after agg1
  k_agg<0><<<aggBlocks, 256, 0, stream>>>(h, nullptr, rowoff, csr, dinv, g, N);
  k_gemm<HFEAT, true><<<dim3(nbG, 2), 256, 0, stream>>>(g, Wmu, Wls, bmu, bls,
                                                        out, out + (size_t)N*HFEAT, N);
}

// Round 4
// 414.724 us; speedup vs baseline: 11.8561x; 11.8561x over previous
//
#include <hip/hip_runtime.h>
#include <hip/hip_bf16.h>
#include <cstdint>

#define HFEAT 128
#define CIN   256

// ---------------- CSR build ----------------

__global__ void k_zero_i32(int* __restrict__ p, int n){
  int i = blockIdx.x*blockDim.x + threadIdx.x;
  if (i < n) p[i] = 0;
}

__global__ void k_count(const int* __restrict__ dst, int E, int* __restrict__ counts){
  int e = blockIdx.x*blockDim.x + threadIdx.x;
  if (e < E) atomicAdd(&counts[dst[e]], 1);
}

__global__ void k_dinv(const int* __restrict__ counts, int n, float* __restrict__ dinv){
  int i = blockIdx.x*blockDim.x + threadIdx.x;
  if (i < n) dinv[i] = rsqrtf((float)counts[i] + 1.0f);
}

__global__ void k_scan1(const int* __restrict__ counts, int n,
                        int* __restrict__ excl, int* __restrict__ bsum){
  __shared__ int sm[1024];
  int t = threadIdx.x;
  int i = blockIdx.x*1024 + t;
  int v = (i < n) ? counts[i] : 0;
  sm[t] = v;
  __syncthreads();
  for (int off = 1; off < 1024; off <<= 1){
    int add = (t >= off) ? sm[t-off] : 0;
    __syncthreads();
    sm[t] += add;
    __syncthreads();
  }
  if (i < n) excl[i] = sm[t] - v;
  if (t == 1023) bsum[blockIdx.x] = sm[t];
}

__global__ void k_scan2(int* __restrict__ bsum, int nb){
  if (threadIdx.x == 0 && blockIdx.x == 0){
    int run = 0;
    for (int b = 0; b < nb; b++){ int v = bsum[b]; bsum[b] = run; run += v; }
  }
}

__global__ void k_scan3(const int* __restrict__ bsum, int n, int E,
                        int* __restrict__ rowoff, int* __restrict__ cursor){
  int i = blockIdx.x*blockDim.x + threadIdx.x;   // blockDim == 1024
  if (i < n){
    int v = rowoff[i] + bsum[blockIdx.x];
    rowoff[i] = v;
    cursor[i] = v;
  }
  if (i == 0) rowoff[n] = E;
}

__global__ void k_fill(const int* __restrict__ src, const int* __restrict__ dst, int E,
                       const float* __restrict__ dinv, int* __restrict__ cursor,
                       int2* __restrict__ csr){
  int e = blockIdx.x*blockDim.x + threadIdx.x;
  if (e < E){
    int s = src[e], d = dst[e];
    int pos = atomicAdd(&cursor[d], 1);
    csr[pos] = make_int2(s, __float_as_int(dinv[s]*dinv[d]));
  }
}

// ---------------- Tiled GEMM (fp32 vector ALU, LDS-staged) ----------------
// C[64 x 128] tile per 256-thread block; thread computes 4 rows x 8 cols
// (cols 4cg..4cg+3 and 64+4cg..64+4cg+3  -> W reads 2-way-bank = free).
// K-tiles of 32. x-tile padded [64][36]; W-tile [32][32] float4.
// Only x prefetched to regs (8 VGPR); no launch_bounds occupancy cap (r3 spill lesson).

template<int K, bool BIAS>
__global__ void __launch_bounds__(256) k_gemm(const float* __restrict__ A,
                                              const float* __restrict__ Wa,
                                              const float* __restrict__ Wb,
                                              const float* __restrict__ ba,
                                              const float* __restrict__ bb,
                                              float* __restrict__ Ca,
                                              float* __restrict__ Cb,
                                              int n){
  __shared__ float  lds_x[64][36];
  __shared__ float4 lds_w[32][32];

  const float* W    = (blockIdx.y == 0) ? Wa : Wb;
  const float* bias = (blockIdx.y == 0) ? ba : bb;
  float*       C    = (blockIdx.y == 0) ? Ca : Cb;

  const int tid  = threadIdx.x;
  const int cg   = tid & 15;          // col group: cols 4cg and 64+4cg
  const int rg   = tid >> 4;          // row group: rows rg*4 .. rg*4+3
  const int row0 = blockIdx.x * 64;
  const int r0   = rg * 4;

  // staging maps (coalesced)
  const int xrow = tid >> 3;          // x rows 0..31 (+32)
  const int xkq  = tid & 7;           // float4 idx in 32-wide k chunk
  const int wr   = tid >> 5;          // W rows 0..7 (+8j)
  const int wc   = tid & 31;          // float4 col idx

  int xra = row0 + xrow;        if (xra >= n) xra = n - 1;
  int xrb = row0 + xrow + 32;   if (xrb >= n) xrb = n - 1;
  const float* Axa = A + (size_t)xra * K + xkq * 4;
  const float* Axb = A + (size_t)xrb * K + xkq * 4;
  const float* Wp  = W + (size_t)wr * HFEAT + wc * 4;

  float acc[4][8];
  #pragma unroll
  for (int i = 0; i < 4; i++)
    #pragma unroll
    for (int j = 0; j < 8; j++) acc[i][j] = 0.f;

  const int NT = K / 32;
  float4 px0 = *(const float4*)(Axa);
  float4 px1 = *(const float4*)(Axb);

  for (int t = 0; t < NT; ++t){
    // W loads first (in flight while x LDS-writes retire)
    const float* wt = Wp + (size_t)t * 32 * HFEAT;
    float4 pw0 = *(const float4*)(wt);
    float4 pw1 = *(const float4*)(wt +  8 * HFEAT);
    float4 pw2 = *(const float4*)(wt + 16 * HFEAT);
    float4 pw3 = *(const float4*)(wt + 24 * HFEAT);

    *(float4*)&lds_x[xrow     ][xkq * 4] = px0;
    *(float4*)&lds_x[xrow + 32][xkq * 4] = px1;
    lds_w[wr     ][wc] = pw0;
    lds_w[wr +  8][wc] = pw1;
    lds_w[wr + 16][wc] = pw2;
    lds_w[wr + 24][wc] = pw3;
    __syncthreads();

    // prefetch next x-tile (cheap: 8 VGPRs)
    if (t + 1 < NT){
      px0 = *(const float4*)(Axa + (t + 1) * 32);
      px1 = *(const float4*)(Axb + (t + 1) * 32);
    }

    #pragma unroll
    for (int k4 = 0; k4 < 8; ++k4){
      const int k = k4 * 4;
      float4 xv[4];
      #pragma unroll
      for (int i = 0; i < 4; i++) xv[i] = *(const float4*)&lds_x[r0 + i][k];
      #pragma unroll
      for (int kk = 0; kk < 4; kk++){
        float4 w0 = lds_w[k + kk][cg];        // cols 4cg..4cg+3
        float4 w1 = lds_w[k + kk][cg + 16];   // cols 64+4cg..
        #pragma unroll
        for (int i = 0; i < 4; i++){
          float xs = (kk == 0) ? xv[i].x : (kk == 1) ? xv[i].y : (kk == 2) ? xv[i].z : xv[i].w;
          acc[i][0] = fmaf(xs, w0.x, acc[i][0]);
          acc[i][1] = fmaf(xs, w0.y, acc[i][1]);
          acc[i][2] = fmaf(xs, w0.z, acc[i][2]);
          acc[i][3] = fmaf(xs, w0.w, acc[i][3]);
          acc[i][4] = fmaf(xs, w1.x, acc[i][4]);
          acc[i][5] = fmaf(xs, w1.y, acc[i][5]);
          acc[i][6] = fmaf(xs, w1.z, acc[i][6]);
          acc[i][7] = fmaf(xs, w1.w, acc[i][7]);
        }
      }
    }
    __syncthreads();
  }

  const int c0 = cg * 4;
  float4 bv0 = make_float4(0,0,0,0), bv1 = make_float4(0,0,0,0);
  if (BIAS){
    bv0 = *(const float4*)&bias[c0];
    bv1 = *(const float4*)&bias[c0 + 64];
  }
  #pragma unroll
  for (int i = 0; i < 4; i++){
    int r = row0 + r0 + i;
    if (r < n){
      float4 o0 = make_float4(acc[i][0] + bv0.x, acc[i][1] + bv0.y,
                              acc[i][2] + bv0.z, acc[i][3] + bv0.w);
      float4 o1 = make_float4(acc[i][4] + bv1.x, acc[i][5] + bv1.y,
                              acc[i][6] + bv1.z, acc[i][7] + bv1.w);
      *(float4*)&C[(size_t)r * HFEAT + c0]      = o0;
      *(float4*)&C[(size_t)r * HFEAT + c0 + 64] = o1;
    }
  }
}

// ---------------- Aggregation: out = A_norm @ in (one wave per node) ----------------

template<int RELU>
__global__ void __launch_bounds__(256) k_agg(const float* __restrict__ in,
                                             const float* __restrict__ bias,
                                             const int* __restrict__ rowoff,
                                             const int2* __restrict__ csr,
                                             const float* __restrict__ dinv,
                                             float* __restrict__ out, int n){
  int gid = blockIdx.x*blockDim.x + threadIdx.x;
  int node = gid >> 6;
  int lane = gid & 63;
  if (node >= n) return;
  float di = dinv[node];
  float sw = di * di;
  int f0 = lane * 2;
  float2 sv = *(const float2*)(in + (size_t)node * HFEAT + f0);
  float ax = sv.x * sw, ay = sv.y * sw;
  int e = rowoff[node], e1 = rowoff[node+1];
  for (; e + 2 <= e1; e += 2){
    int2 c0 = csr[e], c1 = csr[e+1];
    float w0 = __int_as_float(c0.y), w1 = __int_as_float(c1.y);
    float2 v0 = *(const float2*)(in + (size_t)c0.x * HFEAT + f0);
    float2 v1 = *(const float2*)(in + (size_t)c1.x * HFEAT + f0);
    ax = fmaf(v0.x, w0, ax); ay = fmaf(v0.y, w0, ay);
    ax = fmaf(v1.x, w1, ax); ay = fmaf(v1.y, w1, ay);
  }
  if (e < e1){
    int2 c0 = csr[e];
    float w0 = __int_as_float(c0.y);
    float2 v0 = *(const float2*)(in + (size_t)c0.x * HFEAT + f0);
    ax = fmaf(v0.x, w0, ax); ay = fmaf(v0.y, w0, ay);
  }
  if (RELU){
    ax = fmaxf(ax + bias[f0],   0.f);
    ay = fmaxf(ay + bias[f0+1], 0.f);
  }
  *(float2*)(out + (size_t)node * HFEAT + f0) = make_float2(ax, ay);
}

// ---------------- launch ----------------

extern "C" void kernel_launch(void* const* d_in, const int* in_sizes, int n_in,
                              void* d_out, int out_size, void* d_ws, size_t ws_size,
                              hipStream_t stream){
  const float* x   = (const float*)d_in[0];
  const int*   ei  = (const int*)  d_in[1];
  const float* W1  = (const float*)d_in[2];
  const float* b1  = (const float*)d_in[3];
  const float* Wmu = (const float*)d_in[4];
  const float* bmu = (const float*)d_in[5];
  const float* Wls = (const float*)d_in[6];
  const float* bls = (const float*)d_in[7];
  int N = in_sizes[0] / CIN;
  int E = in_sizes[1] / 2;
  const int* src = ei;
  const int* dst = ei + E;
  float* out = (float*)d_out;

  char* w = (char*)d_ws;
  auto alloc = [&](size_t bytes)->char*{
    char* p = w; w += (bytes + 255) & ~(size_t)255; return p;
  };
  float* hW1   = (float*)alloc((size_t)N*HFEAT*4);   // later reused as g
  float* h     = (float*)alloc((size_t)N*HFEAT*4);
  int*   counts= (int*)  alloc((size_t)N*4);
  float* dinv  = (float*)alloc((size_t)N*4);
  int*   rowoff= (int*)  alloc(((size_t)N+1)*4);
  int*   cursor= (int*)  alloc((size_t)N*4);
  int*   bsum  = (int*)  alloc(256*4);
  int2*  csr   = (int2*) alloc((size_t)E*8);

  int nbN  = (N + 255) / 256;
  int nbE  = (E + 255) / 256;
  int nbS  = (N + 1023) / 1024;
  int nbG  = (N + 63) / 64;

  k_zero_i32<<<nbN, 256, 0, stream>>>(counts, N);
  k_count   <<<nbE, 256, 0, stream>>>(dst, E, counts);
  k_dinv    <<<nbN, 256, 0, stream>>>(counts, N, dinv);
  k_scan1   <<<nbS, 1024, 0, stream>>>(counts, N, rowoff, bsum);
  k_scan2   <<<1, 64, 0, stream>>>(bsum, nbS);
  k_scan3   <<<nbS, 1024, 0, stream>>>(bsum, N, E, rowoff, cursor);
  k_fill    <<<nbE, 256, 0, stream>>>(src, dst, E, dinv, cursor, csr);

  k_gemm<CIN, false><<<dim3(nbG, 1), 256, 0, stream>>>(x, W1, W1, nullptr, nullptr, hW1, hW1, N);
  int aggBlocks = (int)(((size_t)N*64 + 255) / 256);
  k_agg<1><<<aggBlocks, 256, 0, stream>>>(hW1, b1, rowoff, csr, dinv, h, N);
  float* g = hW1;  // hW1 dead after agg1
  k_agg<0><<<aggBlocks, 256, 0, stream>>>(h, nullptr, rowoff, csr, dinv, g, N);
  k_gemm<HFEAT, true><<<dim3(nbG, 2), 256, 0, stream>>>(g, Wmu, Wls, bmu, bls,
                                                        out, out + (size_t)N*HFEAT, N);
}

// Round 5
// 401.889 us; speedup vs baseline: 12.2348x; 1.0319x over previous
//
#include <hip/hip_runtime.h>
#include <hip/hip_bf16.h>
#include <cstdint>

#define HFEAT 128
#define CIN   256

// ---------------- CSR build ----------------

__global__ void k_zero_i32(int* __restrict__ p, int n){
  int i = blockIdx.x*blockDim.x + threadIdx.x;
  if (i < n) p[i] = 0;
}

__global__ void k_count(const int* __restrict__ dst, int E, int* __restrict__ counts){
  int e = blockIdx.x*blockDim.x + threadIdx.x;
  if (e < E) atomicAdd(&counts[dst[e]], 1);
}

__global__ void k_dinv(const int* __restrict__ counts, int n, float* __restrict__ dinv){
  int i = blockIdx.x*blockDim.x + threadIdx.x;
  if (i < n) dinv[i] = rsqrtf((float)counts[i] + 1.0f);
}

__global__ void k_scan1(const int* __restrict__ counts, int n,
                        int* __restrict__ excl, int* __restrict__ bsum){
  __shared__ int sm[1024];
  int t = threadIdx.x;
  int i = blockIdx.x*1024 + t;
  int v = (i < n) ? counts[i] : 0;
  sm[t] = v;
  __syncthreads();
  for (int off = 1; off < 1024; off <<= 1){
    int add = (t >= off) ? sm[t-off] : 0;
    __syncthreads();
    sm[t] += add;
    __syncthreads();
  }
  if (i < n) excl[i] = sm[t] - v;
  if (t == 1023) bsum[blockIdx.x] = sm[t];
}

__global__ void k_scan2(int* __restrict__ bsum, int nb){
  if (threadIdx.x == 0 && blockIdx.x == 0){
    int run = 0;
    for (int b = 0; b < nb; b++){ int v = bsum[b]; bsum[b] = run; run += v; }
  }
}

__global__ void k_scan3(const int* __restrict__ bsum, int n, int E,
                        int* __restrict__ rowoff, int* __restrict__ cursor){
  int i = blockIdx.x*blockDim.x + threadIdx.x;   // blockDim == 1024
  if (i < n){
    int v = rowoff[i] + bsum[blockIdx.x];
    rowoff[i] = v;
    cursor[i] = v;
  }
  if (i == 0) rowoff[n] = E;
}

__global__ void k_fill(const int* __restrict__ src, const int* __restrict__ dst, int E,
                       const float* __restrict__ dinv, int* __restrict__ cursor,
                       int2* __restrict__ csr){
  int e = blockIdx.x*blockDim.x + threadIdx.x;
  if (e < E){
    int s = src[e], d = dst[e];
    int pos = atomicAdd(&cursor[d], 1);
    csr[pos] = make_int2(s, __float_as_int(dinv[s]*dinv[d]));
  }
}

// ---------------- Tiled GEMM (fp32 vector ALU, LDS-staged) ----------------
// C[64 x 128] tile per 256-thread block; thread computes 4 rows x 8 cols
// (cols 4cg..4cg+3 and 64+4cg..64+4cg+3  -> W reads 2-way-bank = free).
// K-tiles of 32. x-tile padded [64][36]; W-tile [32][32] float4.
// Only x prefetched to regs (8 VGPR); no launch_bounds occupancy cap (r3 spill lesson).

template<int K, bool BIAS>
__global__ void __launch_bounds__(256) k_gemm(const float* __restrict__ A,
                                              const float* __restrict__ Wa,
                                              const float* __restrict__ Wb,
                                              const float* __restrict__ ba,
                                              const float* __restrict__ bb,
                                              float* __restrict__ Ca,
                                              float* __restrict__ Cb,
                                              int n){
  __shared__ float  lds_x[64][36];
  __shared__ float4 lds_w[32][32];

  const float* W    = (blockIdx.y == 0) ? Wa : Wb;
  const float* bias = (blockIdx.y == 0) ? ba : bb;
  float*       C    = (blockIdx.y == 0) ? Ca : Cb;

  const int tid  = threadIdx.x;
  const int cg   = tid & 15;          // col group: cols 4cg and 64+4cg
  const int rg   = tid >> 4;          // row group: rows rg*4 .. rg*4+3
  const int row0 = blockIdx.x * 64;
  const int r0   = rg * 4;

  // staging maps (coalesced)
  const int xrow = tid >> 3;          // x rows 0..31 (+32)
  const int xkq  = tid & 7;           // float4 idx in 32-wide k chunk
  const int wr   = tid >> 5;          // W rows 0..7 (+8j)
  const int wc   = tid & 31;          // float4 col idx

  int xra = row0 + xrow;        if (xra >= n) xra = n - 1;
  int xrb = row0 + xrow + 32;   if (xrb >= n) xrb = n - 1;
  const float* Axa = A + (size_t)xra * K + xkq * 4;
  const float* Axb = A + (size_t)xrb * K + xkq * 4;
  const float* Wp  = W + (size_t)wr * HFEAT + wc * 4;

  float acc[4][8];
  #pragma unroll
  for (int i = 0; i < 4; i++)
    #pragma unroll
    for (int j = 0; j < 8; j++) acc[i][j] = 0.f;

  const int NT = K / 32;
  float4 px0 = *(const float4*)(Axa);
  float4 px1 = *(const float4*)(Axb);

  for (int t = 0; t < NT; ++t){
    // W loads first (in flight while x LDS-writes retire)
    const float* wt = Wp + (size_t)t * 32 * HFEAT;
    float4 pw0 = *(const float4*)(wt);
    float4 pw1 = *(const float4*)(wt +  8 * HFEAT);
    float4 pw2 = *(const float4*)(wt + 16 * HFEAT);
    float4 pw3 = *(const float4*)(wt + 24 * HFEAT);

    *(float4*)&lds_x[xrow     ][xkq * 4] = px0;
    *(float4*)&lds_x[xrow + 32][xkq * 4] = px1;
    lds_w[wr     ][wc] = pw0;
    lds_w[wr +  8][wc] = pw1;
    lds_w[wr + 16][wc] = pw2;
    lds_w[wr + 24][wc] = pw3;
    __syncthreads();

    // prefetch next x-tile (cheap: 8 VGPRs)
    if (t + 1 < NT){
      px0 = *(const float4*)(Axa + (t + 1) * 32);
      px1 = *(const float4*)(Axb + (t + 1) * 32);
    }

    #pragma unroll
    for (int k4 = 0; k4 < 8; ++k4){
      const int k = k4 * 4;
      float4 xv[4];
      #pragma unroll
      for (int i = 0; i < 4; i++) xv[i] = *(const float4*)&lds_x[r0 + i][k];
      #pragma unroll
      for (int kk = 0; kk < 4; kk++){
        float4 w0 = lds_w[k + kk][cg];        // cols 4cg..4cg+3
        float4 w1 = lds_w[k + kk][cg + 16];   // cols 64+4cg..
        #pragma unroll
        for (int i = 0; i < 4; i++){
          float xs = (kk == 0) ? xv[i].x : (kk == 1) ? xv[i].y : (kk == 2) ? xv[i].z : xv[i].w;
          acc[i][0] = fmaf(xs, w0.x, acc[i][0]);
          acc[i][1] = fmaf(xs, w0.y, acc[i][1]);
          acc[i][2] = fmaf(xs, w0.z, acc[i][2]);
          acc[i][3] = fmaf(xs, w0.w, acc[i][3]);
          acc[i][4] = fmaf(xs, w1.x, acc[i][4]);
          acc[i][5] = fmaf(xs, w1.y, acc[i][5]);
          acc[i][6] = fmaf(xs, w1.z, acc[i][6]);
          acc[i][7] = fmaf(xs, w1.w, acc[i][7]);
        }
      }
    }
    __syncthreads();
  }

  const int c0 = cg * 4;
  float4 bv0 = make_float4(0,0,0,0), bv1 = make_float4(0,0,0,0);
  if (BIAS){
    bv0 = *(const float4*)&bias[c0];
    bv1 = *(const float4*)&bias[c0 + 64];
  }
  #pragma unroll
  for (int i = 0; i < 4; i++){
    int r = row0 + r0 + i;
    if (r < n){
      float4 o0 = make_float4(acc[i][0] + bv0.x, acc[i][1] + bv0.y,
                              acc[i][2] + bv0.z, acc[i][3] + bv0.w);
      float4 o1 = make_float4(acc[i][4] + bv1.x, acc[i][5] + bv1.y,
                              acc[i][6] + bv1.z, acc[i][7] + bv1.w);
      *(float4*)&C[(size_t)r * HFEAT + c0]      = o0;
      *(float4*)&C[(size_t)r * HFEAT + c0 + 64] = o1;
    }
  }
}

// ---------------- Aggregation: out = A_norm @ in ----------------
// One wave per node. Each HALF-wave (32 lanes x float4 = 512B) gathers one
// full source row; 2 edges concurrent per wave, 4 per iteration, unroll 2
// -> up to 8 independent row-gathers in flight (latency hiding; r4 lesson:
// VALUBusy 19% + hbm 43% = latency-bound at 2 loads/wave).
// Halves combined at the end via __shfl_xor(...,32).

template<int RELU>
__global__ void __launch_bounds__(256) k_agg(const float* __restrict__ in,
                                             const float* __restrict__ bias,
                                             const int* __restrict__ rowoff,
                                             const int2* __restrict__ csr,
                                             const float* __restrict__ dinv,
                                             float* __restrict__ out, int n){
  int gid  = blockIdx.x*blockDim.x + threadIdx.x;
  int node = gid >> 6;
  int lane = gid & 63;
  if (node >= n) return;
  const int half = lane >> 5;      // 0/1: which edge of the pair
  const int q    = lane & 31;      // float4 slot within the row
  const int f0   = q * 4;

  float4 acc = make_float4(0.f, 0.f, 0.f, 0.f);

  const int e0 = rowoff[node], e1 = rowoff[node+1];
  const int deg = e1 - e0;
  const int rem = deg & 3;
  const int mainEnd = e1 - rem;

  #pragma unroll 2
  for (int base = e0; base < mainEnd; base += 4){
    int2 ca = csr[base + half*2];
    int2 cb = csr[base + half*2 + 1];
    float4 va = *(const float4*)(in + (size_t)ca.x * HFEAT + f0);
    float4 vb = *(const float4*)(in + (size_t)cb.x * HFEAT + f0);
    float wa = __int_as_float(ca.y), wb = __int_as_float(cb.y);
    acc.x = fmaf(va.x, wa, acc.x); acc.y = fmaf(va.y, wa, acc.y);
    acc.z = fmaf(va.z, wa, acc.z); acc.w = fmaf(va.w, wa, acc.w);
    acc.x = fmaf(vb.x, wb, acc.x); acc.y = fmaf(vb.y, wb, acc.y);
    acc.z = fmaf(vb.z, wb, acc.z); acc.w = fmaf(vb.w, wb, acc.w);
  }
  // remainder (0..3 edges): half 0 takes even slots, half 1 odd
  for (int ee = mainEnd + half; ee < e1; ee += 2){
    int2 c = csr[ee];
    float4 v = *(const float4*)(in + (size_t)c.x * HFEAT + f0);
    float wv = __int_as_float(c.y);
    acc.x = fmaf(v.x, wv, acc.x); acc.y = fmaf(v.y, wv, acc.y);
    acc.z = fmaf(v.z, wv, acc.z); acc.w = fmaf(v.w, wv, acc.w);
  }
  // self-loop on half 0 only (counted once after combine)
  if (half == 0){
    float di = dinv[node];
    float sw = di * di;
    float4 sv = *(const float4*)(in + (size_t)node * HFEAT + f0);
    acc.x = fmaf(sv.x, sw, acc.x); acc.y = fmaf(sv.y, sw, acc.y);
    acc.z = fmaf(sv.z, sw, acc.z); acc.w = fmaf(sv.w, sw, acc.w);
  }
  // combine halves
  acc.x += __shfl_xor(acc.x, 32);
  acc.y += __shfl_xor(acc.y, 32);
  acc.z += __shfl_xor(acc.z, 32);
  acc.w += __shfl_xor(acc.w, 32);

  if (RELU){
    float4 bv = *(const float4*)&bias[f0];
    acc.x = fmaxf(acc.x + bv.x, 0.f);
    acc.y = fmaxf(acc.y + bv.y, 0.f);
    acc.z = fmaxf(acc.z + bv.z, 0.f);
    acc.w = fmaxf(acc.w + bv.w, 0.f);
  }
  if (half == 0)
    *(float4*)(out + (size_t)node * HFEAT + f0) = acc;
}

// ---------------- launch ----------------

extern "C" void kernel_launch(void* const* d_in, const int* in_sizes, int n_in,
                              void* d_out, int out_size, void* d_ws, size_t ws_size,
                              hipStream_t stream){
  const float* x   = (const float*)d_in[0];
  const int*   ei  = (const int*)  d_in[1];
  const float* W1  = (const float*)d_in[2];
  const float* b1  = (const float*)d_in[3];
  const float* Wmu = (const float*)d_in[4];
  const float* bmu = (const float*)d_in[5];
  const float* Wls = (const float*)d_in[6];
  const float* bls = (const float*)d_in[7];
  int N = in_sizes[0] / CIN;
  int E = in_sizes[1] / 2;
  const int* src = ei;
  const int* dst = ei + E;
  float* out = (float*)d_out;

  char* w = (char*)d_ws;
  auto alloc = [&](size_t bytes)->char*{
    char* p = w; w += (bytes + 255) & ~(size_t)255; return p;
  };
  float* hW1   = (float*)alloc((size_t)N*HFEAT*4);   // later reused as g
  float* h     = (float*)alloc((size_t)N*HFEAT*4);
  int*   counts= (int*)  alloc((size_t)N*4);
  float* dinv  = (float*)alloc((size_t)N*4);
  int*   rowoff= (int*)  alloc(((size_t)N+1)*4);
  int*   cursor= (int*)  alloc((size_t)N*4);
  int*   bsum  = (int*)  alloc(256*4);
  int2*  csr   = (int2*) alloc((size_t)E*8);

  int nbN  = (N + 255) / 256;
  int nbE  = (E + 255) / 256;
  int nbS  = (N + 1023) / 1024;
  int nbG  = (N + 63) / 64;

  k_zero_i32<<<nbN, 256, 0, stream>>>(counts, N);
  k_count   <<<nbE, 256, 0, stream>>>(dst, E, counts);
  k_dinv    <<<nbN, 256, 0, stream>>>(counts, N, dinv);
  k_scan1   <<<nbS, 1024, 0, stream>>>(counts, N, rowoff, bsum);
  k_scan2   <<<1, 64, 0, stream>>>(bsum, nbS);
  k_scan3   <<<nbS, 1024, 0, stream>>>(bsum, N, E, rowoff, cursor);
  k_fill    <<<nbE, 256, 0, stream>>>(src, dst, E, dinv, cursor, csr);

  k_gemm<CIN, false><<<dim3(nbG, 1), 256, 0, stream>>>(x, W1, W1, nullptr, nullptr, hW1, hW1, N);
  int aggBlocks = (int)(((size_t)N*64 + 255) / 256);
  k_agg<1><<<aggBlocks, 256, 0, stream>>>(hW1, b1, rowoff, csr, dinv, h, N);
  float* g = hW1;  // hW1 dead after agg1
  k_agg<0><<<aggBlocks, 256, 0, stream>>>(h, nullptr, rowoff, csr, dinv, g, N);
  k_gemm<HFEAT, true><<<dim3(nbG, 2), 256, 0, stream>>>(g, Wmu, Wls, bmu, bls,
                                                        out, out + (size_t)N*HFEAT, N);
}

// Round 6
// 367.291 us; speedup vs baseline: 13.3873x; 1.0942x over previous
//
#include <hip/hip_runtime.h>
#include <hip/hip_bf16.h>
#include <cstdint>

#define HFEAT 128
#define CIN   256

typedef unsigned int  uint;
typedef unsigned short ushort;

__device__ inline float bflo(uint u){ return __uint_as_float(u << 16); }
__device__ inline float bfhi(uint u){ return __uint_as_float(u & 0xffff0000u); }
__device__ inline uint  f2bf(float f){
  union { __hip_bfloat16 b; ushort u; } cvt;
  cvt.b = __float2bfloat16(f);   // RNE
  return (uint)cvt.u;
}

// ---------------- CSR build ----------------

__global__ void k_zero_i32(int* __restrict__ p, int n){
  int i = blockIdx.x*blockDim.x + threadIdx.x;
  if (i < n) p[i] = 0;
}

__global__ void k_count(const int* __restrict__ dst, int E, int* __restrict__ counts){
  int e = blockIdx.x*blockDim.x + threadIdx.x;
  if (e < E) atomicAdd(&counts[dst[e]], 1);
}

__global__ void k_dinv(const int* __restrict__ counts, int n, float* __restrict__ dinv){
  int i = blockIdx.x*blockDim.x + threadIdx.x;
  if (i < n) dinv[i] = rsqrtf((float)counts[i] + 1.0f);
}

__global__ void k_scan1(const int* __restrict__ counts, int n,
                        int* __restrict__ excl, int* __restrict__ bsum){
  __shared__ int sm[1024];
  int t = threadIdx.x;
  int i = blockIdx.x*1024 + t;
  int v = (i < n) ? counts[i] : 0;
  sm[t] = v;
  __syncthreads();
  for (int off = 1; off < 1024; off <<= 1){
    int add = (t >= off) ? sm[t-off] : 0;
    __syncthreads();
    sm[t] += add;
    __syncthreads();
  }
  if (i < n) excl[i] = sm[t] - v;
  if (t == 1023) bsum[blockIdx.x] = sm[t];
}

__global__ void k_scan2(int* __restrict__ bsum, int nb){
  if (threadIdx.x == 0 && blockIdx.x == 0){
    int run = 0;
    for (int b = 0; b < nb; b++){ int v = bsum[b]; bsum[b] = run; run += v; }
  }
}

__global__ void k_scan3(const int* __restrict__ bsum, int n, int E,
                        int* __restrict__ rowoff, int* __restrict__ cursor){
  int i = blockIdx.x*blockDim.x + threadIdx.x;   // blockDim == 1024
  if (i < n){
    int v = rowoff[i] + bsum[blockIdx.x];
    rowoff[i] = v;
    cursor[i] = v;
  }
  if (i == 0) rowoff[n] = E;
}

__global__ void k_fill(const int* __restrict__ src, const int* __restrict__ dst, int E,
                       const float* __restrict__ dinv, int* __restrict__ cursor,
                       int2* __restrict__ csr){
  int e = blockIdx.x*blockDim.x + threadIdx.x;
  if (e < E){
    int s = src[e], d = dst[e];
    int pos = atomicAdd(&cursor[d], 1);
    csr[pos] = make_int2(s, __float_as_int(dinv[s]*dinv[d]));
  }
}

// ---------------- Tiled GEMM (fp32 vector ALU, LDS-staged) ----------------
// C[64 x 128] tile per 256-thread block; thread computes 4 rows x 8 cols
// (cols 4cg..4cg+3 and 64+4cg..64+4cg+3 -> W reads 2-way-bank = free).
// OUT_BF16 packs each 4-col group into uint2 (8B) stores.

template<int K, bool BIAS, bool OUT_BF16>
__global__ void __launch_bounds__(256) k_gemm(const float* __restrict__ A,
                                              const float* __restrict__ Wa,
                                              const float* __restrict__ Wb,
                                              const float* __restrict__ ba,
                                              const float* __restrict__ bb,
                                              void* __restrict__ Cva,
                                              void* __restrict__ Cvb,
                                              int n){
  __shared__ float  lds_x[64][36];
  __shared__ float4 lds_w[32][32];

  const float* W    = (blockIdx.y == 0) ? Wa : Wb;
  const float* bias = (blockIdx.y == 0) ? ba : bb;
  void*        Cv   = (blockIdx.y == 0) ? Cva : Cvb;

  const int tid  = threadIdx.x;
  const int cg   = tid & 15;
  const int rg   = tid >> 4;
  const int row0 = blockIdx.x * 64;
  const int r0   = rg * 4;

  const int xrow = tid >> 3;
  const int xkq  = tid & 7;
  const int wr   = tid >> 5;
  const int wc   = tid & 31;

  int xra = row0 + xrow;        if (xra >= n) xra = n - 1;
  int xrb = row0 + xrow + 32;   if (xrb >= n) xrb = n - 1;
  const float* Axa = A + (size_t)xra * K + xkq * 4;
  const float* Axb = A + (size_t)xrb * K + xkq * 4;
  const float* Wp  = W + (size_t)wr * HFEAT + wc * 4;

  float acc[4][8];
  #pragma unroll
  for (int i = 0; i < 4; i++)
    #pragma unroll
    for (int j = 0; j < 8; j++) acc[i][j] = 0.f;

  const int NT = K / 32;
  float4 px0 = *(const float4*)(Axa);
  float4 px1 = *(const float4*)(Axb);

  for (int t = 0; t < NT; ++t){
    const float* wt = Wp + (size_t)t * 32 * HFEAT;
    float4 pw0 = *(const float4*)(wt);
    float4 pw1 = *(const float4*)(wt +  8 * HFEAT);
    float4 pw2 = *(const float4*)(wt + 16 * HFEAT);
    float4 pw3 = *(const float4*)(wt + 24 * HFEAT);

    *(float4*)&lds_x[xrow     ][xkq * 4] = px0;
    *(float4*)&lds_x[xrow + 32][xkq * 4] = px1;
    lds_w[wr     ][wc] = pw0;
    lds_w[wr +  8][wc] = pw1;
    lds_w[wr + 16][wc] = pw2;
    lds_w[wr + 24][wc] = pw3;
    __syncthreads();

    if (t + 1 < NT){
      px0 = *(const float4*)(Axa + (t + 1) * 32);
      px1 = *(const float4*)(Axb + (t + 1) * 32);
    }

    #pragma unroll
    for (int k4 = 0; k4 < 8; ++k4){
      const int k = k4 * 4;
      float4 xv[4];
      #pragma unroll
      for (int i = 0; i < 4; i++) xv[i] = *(const float4*)&lds_x[r0 + i][k];
      #pragma unroll
      for (int kk = 0; kk < 4; kk++){
        float4 w0 = lds_w[k + kk][cg];
        float4 w1 = lds_w[k + kk][cg + 16];
        #pragma unroll
        for (int i = 0; i < 4; i++){
          float xs = (kk == 0) ? xv[i].x : (kk == 1) ? xv[i].y : (kk == 2) ? xv[i].z : xv[i].w;
          acc[i][0] = fmaf(xs, w0.x, acc[i][0]);
          acc[i][1] = fmaf(xs, w0.y, acc[i][1]);
          acc[i][2] = fmaf(xs, w0.z, acc[i][2]);
          acc[i][3] = fmaf(xs, w0.w, acc[i][3]);
          acc[i][4] = fmaf(xs, w1.x, acc[i][4]);
          acc[i][5] = fmaf(xs, w1.y, acc[i][5]);
          acc[i][6] = fmaf(xs, w1.z, acc[i][6]);
          acc[i][7] = fmaf(xs, w1.w, acc[i][7]);
        }
      }
    }
    __syncthreads();
  }

  const int c0 = cg * 4;
  float4 bv0 = make_float4(0,0,0,0), bv1 = make_float4(0,0,0,0);
  if (BIAS){
    bv0 = *(const float4*)&bias[c0];
    bv1 = *(const float4*)&bias[c0 + 64];
  }
  #pragma unroll
  for (int i = 0; i < 4; i++){
    int r = row0 + r0 + i;
    if (r < n){
      float4 o0 = make_float4(acc[i][0] + bv0.x, acc[i][1] + bv0.y,
                              acc[i][2] + bv0.z, acc[i][3] + bv0.w);
      float4 o1 = make_float4(acc[i][4] + bv1.x, acc[i][5] + bv1.y,
                              acc[i][6] + bv1.z, acc[i][7] + bv1.w);
      if (OUT_BF16){
        ushort* C = (ushort*)Cv;
        uint2 p0, p1;
        p0.x = f2bf(o0.x) | (f2bf(o0.y) << 16);
        p0.y = f2bf(o0.z) | (f2bf(o0.w) << 16);
        p1.x = f2bf(o1.x) | (f2bf(o1.y) << 16);
        p1.y = f2bf(o1.z) | (f2bf(o1.w) << 16);
        *(uint2*)&C[(size_t)r * HFEAT + c0]      = p0;
        *(uint2*)&C[(size_t)r * HFEAT + c0 + 64] = p1;
      } else {
        float* C = (float*)Cv;
        *(float4*)&C[(size_t)r * HFEAT + c0]      = o0;
        *(float4*)&C[(size_t)r * HFEAT + c0 + 64] = o1;
      }
    }
  }
}

// ---------------- Aggregation: out = A_norm @ in (bf16 gather table) ----------------
// One wave per node. Each QUARTER-wave (16 lanes x uint4 = 256B) gathers one
// bf16 source row; 4 edges concurrent per wave iteration, unroll 2 -> 8
// gathers in flight. Quarters combined via __shfl_xor(16|32) butterfly.
// r5 lesson: agg is traffic-bound (8 XCD L2 compulsory re-fetch of the
// table) -> halving bytes with bf16 is the lever, not more MLP.

template<int RELU, bool OUT_BF16>
__global__ void __launch_bounds__(256) k_agg(const ushort* __restrict__ in,
                                             const float* __restrict__ bias,
                                             const int* __restrict__ rowoff,
                                             const int2* __restrict__ csr,
                                             const float* __restrict__ dinv,
                                             void* __restrict__ out, int n){
  int gid  = blockIdx.x*blockDim.x + threadIdx.x;
  int node = gid >> 6;
  int lane = gid & 63;
  if (node >= n) return;
  const int w  = lane >> 4;        // quarter 0..3 (edge slot)
  const int q  = lane & 15;        // 16B slot within row
  const int f0 = q * 8;            // first feature of this lane

  float acc[8] = {0,0,0,0,0,0,0,0};

  const int e0 = rowoff[node], e1 = rowoff[node+1];
  #pragma unroll 2
  for (int e = e0 + w; e < e1; e += 4){
    int2 c = csr[e];
    uint4 v = *(const uint4*)(in + ((size_t)c.x << 7) + f0);
    float wv = __int_as_float(c.y);
    acc[0] = fmaf(bflo(v.x), wv, acc[0]);
    acc[1] = fmaf(bfhi(v.x), wv, acc[1]);
    acc[2] = fmaf(bflo(v.y), wv, acc[2]);
    acc[3] = fmaf(bfhi(v.y), wv, acc[3]);
    acc[4] = fmaf(bflo(v.z), wv, acc[4]);
    acc[5] = fmaf(bfhi(v.z), wv, acc[5]);
    acc[6] = fmaf(bflo(v.w), wv, acc[6]);
    acc[7] = fmaf(bfhi(v.w), wv, acc[7]);
  }
  if (w == 0){   // self-loop, counted once
    float di = dinv[node];
    float sw = di * di;
    uint4 v = *(const uint4*)(in + ((size_t)node << 7) + f0);
    acc[0] = fmaf(bflo(v.x), sw, acc[0]);
    acc[1] = fmaf(bfhi(v.x), sw, acc[1]);
    acc[2] = fmaf(bflo(v.y), sw, acc[2]);
    acc[3] = fmaf(bfhi(v.y), sw, acc[3]);
    acc[4] = fmaf(bflo(v.z), sw, acc[4]);
    acc[5] = fmaf(bfhi(v.z), sw, acc[5]);
    acc[6] = fmaf(bflo(v.w), sw, acc[6]);
    acc[7] = fmaf(bfhi(v.w), sw, acc[7]);
  }
  // combine quarters (lane = w*16 + q; xor 16/32 flips quarter bits, keeps q)
  #pragma unroll
  for (int j = 0; j < 8; j++){
    acc[j] += __shfl_xor(acc[j], 16);
    acc[j] += __shfl_xor(acc[j], 32);
  }

  if (RELU){
    float4 b0 = *(const float4*)&bias[f0];
    float4 b1 = *(const float4*)&bias[f0 + 4];
    acc[0] = fmaxf(acc[0] + b0.x, 0.f);
    acc[1] = fmaxf(acc[1] + b0.y, 0.f);
    acc[2] = fmaxf(acc[2] + b0.z, 0.f);
    acc[3] = fmaxf(acc[3] + b0.w, 0.f);
    acc[4] = fmaxf(acc[4] + b1.x, 0.f);
    acc[5] = fmaxf(acc[5] + b1.y, 0.f);
    acc[6] = fmaxf(acc[6] + b1.z, 0.f);
    acc[7] = fmaxf(acc[7] + b1.w, 0.f);
  }

  if (w == 0){
    if (OUT_BF16){
      uint4 p;
      p.x = f2bf(acc[0]) | (f2bf(acc[1]) << 16);
      p.y = f2bf(acc[2]) | (f2bf(acc[3]) << 16);
      p.z = f2bf(acc[4]) | (f2bf(acc[5]) << 16);
      p.w = f2bf(acc[6]) | (f2bf(acc[7]) << 16);
      *(uint4*)((ushort*)out + ((size_t)node << 7) + f0) = p;
    } else {
      float* o = (float*)out + ((size_t)node << 7) + f0;
      *(float4*)o       = make_float4(acc[0], acc[1], acc[2], acc[3]);
      *(float4*)(o + 4) = make_float4(acc[4], acc[5], acc[6], acc[7]);
    }
  }
}

// ---------------- launch ----------------

extern "C" void kernel_launch(void* const* d_in, const int* in_sizes, int n_in,
                              void* d_out, int out_size, void* d_ws, size_t ws_size,
                              hipStream_t stream){
  const float* x   = (const float*)d_in[0];
  const int*   ei  = (const int*)  d_in[1];
  const float* W1  = (const float*)d_in[2];
  const float* b1  = (const float*)d_in[3];
  const float* Wmu = (const float*)d_in[4];
  const float* bmu = (const float*)d_in[5];
  const float* Wls = (const float*)d_in[6];
  const float* bls = (const float*)d_in[7];
  int N = in_sizes[0] / CIN;
  int E = in_sizes[1] / 2;
  const int* src = ei;
  const int* dst = ei + E;
  float* out = (float*)d_out;

  char* w = (char*)d_ws;
  auto alloc = [&](size_t bytes)->char*{
    char* p = w; w += (bytes + 255) & ~(size_t)255; return p;
  };
  ushort* hW1b  = (ushort*)alloc((size_t)N*HFEAT*2);  // bf16 gemm1 out (gather table 1)
  ushort* hb    = (ushort*)alloc((size_t)N*HFEAT*2);  // bf16 h (gather table 2)
  float*  g     = (float*) alloc((size_t)N*HFEAT*4);  // fp32 agg2 out
  int*   counts = (int*)   alloc((size_t)N*4);
  float* dinv   = (float*) alloc((size_t)N*4);
  int*   rowoff = (int*)   alloc(((size_t)N+1)*4);
  int*   cursor = (int*)   alloc((size_t)N*4);
  int*   bsum   = (int*)   alloc(256*4);
  int2*  csr    = (int2*)  alloc((size_t)E*8);

  int nbN  = (N + 255) / 256;
  int nbE  = (E + 255) / 256;
  int nbS  = (N + 1023) / 1024;
  int nbG  = (N + 63) / 64;

  k_zero_i32<<<nbN, 256, 0, stream>>>(counts, N);
  k_count   <<<nbE, 256, 0, stream>>>(dst, E, counts);
  k_dinv    <<<nbN, 256, 0, stream>>>(counts, N, dinv);
  k_scan1   <<<nbS, 1024, 0, stream>>>(counts, N, rowoff, bsum);
  k_scan2   <<<1, 64, 0, stream>>>(bsum, nbS);
  k_scan3   <<<nbS, 1024, 0, stream>>>(bsum, N, E, rowoff, cursor);
  k_fill    <<<nbE, 256, 0, stream>>>(src, dst, E, dinv, cursor, csr);

  k_gemm<CIN, false, true><<<dim3(nbG, 1), 256, 0, stream>>>(
      x, W1, W1, nullptr, nullptr, hW1b, hW1b, N);
  int aggBlocks = (int)(((size_t)N*64 + 255) / 256);
  k_agg<1, true ><<<aggBlocks, 256, 0, stream>>>(hW1b, b1, rowoff, csr, dinv, hb, N);
  k_agg<0, false><<<aggBlocks, 256, 0, stream>>>(hb, nullptr, rowoff, csr, dinv, g, N);
  k_gemm<HFEAT, true, false><<<dim3(nbG, 2), 256, 0, stream>>>(
      g, Wmu, Wls, bmu, bls, out, out + (size_t)N*HFEAT, N);
}

// Round 7
// 325.554 us; speedup vs baseline: 15.1036x; 1.1282x over previous
//
#include <hip/hip_runtime.h>
#include <hip/hip_bf16.h>
#include <cstdint>

#define HFEAT 128
#define CIN   256

typedef unsigned int  uint;
typedef unsigned short ushort;
typedef short bf16x8 __attribute__((ext_vector_type(8)));
typedef float f32x4  __attribute__((ext_vector_type(4)));

__device__ inline float bflo(uint u){ return __uint_as_float(u << 16); }
__device__ inline float bfhi(uint u){ return __uint_as_float(u & 0xffff0000u); }
__device__ inline uint  f2bf(float f){
  union { __hip_bfloat16 b; ushort u; } cvt;
  cvt.b = __float2bfloat16(f);   // RNE
  return (uint)cvt.u;
}

// ---------------- CSR build ----------------

__global__ void k_zero_i32(int* __restrict__ p, int n){
  int i = blockIdx.x*blockDim.x + threadIdx.x;
  if (i < n) p[i] = 0;
}

__global__ void k_count(const int* __restrict__ dst, int E, int* __restrict__ counts){
  int e = blockIdx.x*blockDim.x + threadIdx.x;
  if (e < E) atomicAdd(&counts[dst[e]], 1);
}

__global__ void k_dinv(const int* __restrict__ counts, int n, float* __restrict__ dinv){
  int i = blockIdx.x*blockDim.x + threadIdx.x;
  if (i < n) dinv[i] = rsqrtf((float)counts[i] + 1.0f);
}

__global__ void k_scan1(const int* __restrict__ counts, int n,
                        int* __restrict__ excl, int* __restrict__ bsum){
  __shared__ int sm[1024];
  int t = threadIdx.x;
  int i = blockIdx.x*1024 + t;
  int v = (i < n) ? counts[i] : 0;
  sm[t] = v;
  __syncthreads();
  for (int off = 1; off < 1024; off <<= 1){
    int add = (t >= off) ? sm[t-off] : 0;
    __syncthreads();
    sm[t] += add;
    __syncthreads();
  }
  if (i < n) excl[i] = sm[t] - v;
  if (t == 1023) bsum[blockIdx.x] = sm[t];
}

__global__ void k_scan2(int* __restrict__ bsum, int nb){
  if (threadIdx.x == 0 && blockIdx.x == 0){
    int run = 0;
    for (int b = 0; b < nb; b++){ int v = bsum[b]; bsum[b] = run; run += v; }
  }
}

__global__ void k_scan3(const int* __restrict__ bsum, int n, int E,
                        int* __restrict__ rowoff, int* __restrict__ cursor){
  int i = blockIdx.x*blockDim.x + threadIdx.x;   // blockDim == 1024
  if (i < n){
    int v = rowoff[i] + bsum[blockIdx.x];
    rowoff[i] = v;
    cursor[i] = v;
  }
  if (i == 0) rowoff[n] = E;
}

__global__ void k_fill(const int* __restrict__ src, const int* __restrict__ dst, int E,
                       const float* __restrict__ dinv, int* __restrict__ cursor,
                       int2* __restrict__ csr){
  int e = blockIdx.x*blockDim.x + threadIdx.x;
  if (e < E){
    int s = src[e], d = dst[e];
    int pos = atomicAdd(&cursor[d], 1);
    csr[pos] = make_int2(s, __float_as_int(dinv[s]*dinv[d]));
  }
}

// ---------------- W1 fp32 [256][128] -> bf16 TRANSPOSED [128][256] ----------------

__global__ void k_cvt_wt(const float* __restrict__ W, ushort* __restrict__ Wt){
  int n = blockIdx.x;          // 128 blocks = output row (col of W)
  int k = threadIdx.x;         // 256 threads = output col (row of W)
  Wt[n * CIN + k] = (ushort)f2bf(W[(size_t)k * HFEAT + n]);
}

// ---------------- gemm1: hW1b[N,128](bf16) = x[N,256](fp32) @ W1 via bf16 MFMA ----------
// 64x128 tile / 256-thread block (4 waves); wave w -> rows 16w..16w+15, 8 col-tiles.
// K_TILE=64 staged in LDS: A cvt fp32->bf16 on stage (padded [64][72]);
// B from pre-transposed W1bt (padded [128][72]). Frag reads = ds_read_b128.
// A/B share the same k-index function -> any lane-k-permutation cancels (hedge);
// C/D layout per guide m89: col=lane&15, row=(lane>>4)*4+reg.

__global__ void __launch_bounds__(256) k_gemm1_mfma(const float* __restrict__ x,
                                                    const ushort* __restrict__ Wt,
                                                    ushort* __restrict__ outb,
                                                    int n){
  __shared__ ushort Abuf[64][72];
  __shared__ ushort Bbuf[128][72];

  const int tid  = threadIdx.x;
  const int w    = tid >> 6;
  const int l    = tid & 63;
  const int l15  = l & 15;
  const int lhi  = l >> 4;          // 0..3
  const int row0 = blockIdx.x * 64;

  // A staging map: thread -> (row, 16-float chunk)
  const int ar = tid >> 2;          // 0..63
  const int aq = tid & 3;           // 0..3 (16 floats each)
  int arow = row0 + ar; if (arow >= n) arow = n - 1;
  const float* xp = x + (size_t)arow * CIN + aq * 16;

  f32x4 acc[8];
  #pragma unroll
  for (int t = 0; t < 8; t++) acc[t] = (f32x4){0.f, 0.f, 0.f, 0.f};

  for (int kt = 0; kt < 4; ++kt){
    // stage A: 64 rows x 64 k (fp32 -> bf16)
    {
      const float* p = xp + kt * 64;
      float4 v0 = *(const float4*)(p);
      float4 v1 = *(const float4*)(p + 4);
      float4 v2 = *(const float4*)(p + 8);
      float4 v3 = *(const float4*)(p + 12);
      uint4 pa, pb;
      pa.x = f2bf(v0.x) | (f2bf(v0.y) << 16);
      pa.y = f2bf(v0.z) | (f2bf(v0.w) << 16);
      pa.z = f2bf(v1.x) | (f2bf(v1.y) << 16);
      pa.w = f2bf(v1.z) | (f2bf(v1.w) << 16);
      pb.x = f2bf(v2.x) | (f2bf(v2.y) << 16);
      pb.y = f2bf(v2.z) | (f2bf(v2.w) << 16);
      pb.z = f2bf(v3.x) | (f2bf(v3.y) << 16);
      pb.w = f2bf(v3.z) | (f2bf(v3.w) << 16);
      *(uint4*)&Abuf[ar][aq * 16]     = pa;
      *(uint4*)&Abuf[ar][aq * 16 + 8] = pb;
    }
    // stage B: 128 n x 64 k (bf16 copy)
    #pragma unroll
    for (int j = 0; j < 4; ++j){
      int flat = tid + 256 * j;          // 0..1023
      int bn = flat >> 3;
      int bk = (flat & 7) * 8;
      uint4 v = *(const uint4*)(Wt + (size_t)bn * CIN + kt * 64 + bk);
      *(uint4*)&Bbuf[bn][bk] = v;
    }
    __syncthreads();

    #pragma unroll
    for (int ks = 0; ks < 2; ++ks){
      const int ko = ks * 32 + lhi * 8;
      bf16x8 af = *(bf16x8*)&Abuf[16 * w + l15][ko];
      #pragma unroll
      for (int nt = 0; nt < 8; ++nt){
        bf16x8 bf = *(bf16x8*)&Bbuf[nt * 16 + l15][ko];
        acc[nt] = __builtin_amdgcn_mfma_f32_16x16x32_bf16(af, bf, acc[nt], 0, 0, 0);
      }
    }
    __syncthreads();
  }

  // epilogue: row = row0 + 16w + lhi*4 + j, col = nt*16 + l15
  #pragma unroll
  for (int j = 0; j < 4; ++j){
    int r = row0 + 16 * w + lhi * 4 + j;
    if (r < n){
      ushort* orow = outb + (size_t)r * HFEAT + l15;
      #pragma unroll
      for (int nt = 0; nt < 8; ++nt)
        orow[nt * 16] = (ushort)f2bf(acc[nt][j]);
    }
  }
}

// ---------------- Tiled fp32 GEMM (gemm2: mu/logstd) ----------------

template<int K, bool BIAS, bool OUT_BF16>
__global__ void __launch_bounds__(256) k_gemm(const float* __restrict__ A,
                                              const float* __restrict__ Wa,
                                              const float* __restrict__ Wb,
                                              const float* __restrict__ ba,
                                              const float* __restrict__ bb,
                                              void* __restrict__ Cva,
                                              void* __restrict__ Cvb,
                                              int n){
  __shared__ float  lds_x[64][36];
  __shared__ float4 lds_w[32][32];

  const float* W    = (blockIdx.y == 0) ? Wa : Wb;
  const float* bias = (blockIdx.y == 0) ? ba : bb;
  void*        Cv   = (blockIdx.y == 0) ? Cva : Cvb;

  const int tid  = threadIdx.x;
  const int cg   = tid & 15;
  const int rg   = tid >> 4;
  const int row0 = blockIdx.x * 64;
  const int r0   = rg * 4;

  const int xrow = tid >> 3;
  const int xkq  = tid & 7;
  const int wr   = tid >> 5;
  const int wc   = tid & 31;

  int xra = row0 + xrow;        if (xra >= n) xra = n - 1;
  int xrb = row0 + xrow + 32;   if (xrb >= n) xrb = n - 1;
  const float* Axa = A + (size_t)xra * K + xkq * 4;
  const float* Axb = A + (size_t)xrb * K + xkq * 4;
  const float* Wp  = W + (size_t)wr * HFEAT + wc * 4;

  float acc[4][8];
  #pragma unroll
  for (int i = 0; i < 4; i++)
    #pragma unroll
    for (int j = 0; j < 8; j++) acc[i][j] = 0.f;

  const int NT = K / 32;
  float4 px0 = *(const float4*)(Axa);
  float4 px1 = *(const float4*)(Axb);

  for (int t = 0; t < NT; ++t){
    const float* wt = Wp + (size_t)t * 32 * HFEAT;
    float4 pw0 = *(const float4*)(wt);
    float4 pw1 = *(const float4*)(wt +  8 * HFEAT);
    float4 pw2 = *(const float4*)(wt + 16 * HFEAT);
    float4 pw3 = *(const float4*)(wt + 24 * HFEAT);

    *(float4*)&lds_x[xrow     ][xkq * 4] = px0;
    *(float4*)&lds_x[xrow + 32][xkq * 4] = px1;
    lds_w[wr     ][wc] = pw0;
    lds_w[wr +  8][wc] = pw1;
    lds_w[wr + 16][wc] = pw2;
    lds_w[wr + 24][wc] = pw3;
    __syncthreads();

    if (t + 1 < NT){
      px0 = *(const float4*)(Axa + (t + 1) * 32);
      px1 = *(const float4*)(Axb + (t + 1) * 32);
    }

    #pragma unroll
    for (int k4 = 0; k4 < 8; ++k4){
      const int k = k4 * 4;
      float4 xv[4];
      #pragma unroll
      for (int i = 0; i < 4; i++) xv[i] = *(const float4*)&lds_x[r0 + i][k];
      #pragma unroll
      for (int kk = 0; kk < 4; kk++){
        float4 w0 = lds_w[k + kk][cg];
        float4 w1 = lds_w[k + kk][cg + 16];
        #pragma unroll
        for (int i = 0; i < 4; i++){
          float xs = (kk == 0) ? xv[i].x : (kk == 1) ? xv[i].y : (kk == 2) ? xv[i].z : xv[i].w;
          acc[i][0] = fmaf(xs, w0.x, acc[i][0]);
          acc[i][1] = fmaf(xs, w0.y, acc[i][1]);
          acc[i][2] = fmaf(xs, w0.z, acc[i][2]);
          acc[i][3] = fmaf(xs, w0.w, acc[i][3]);
          acc[i][4] = fmaf(xs, w1.x, acc[i][4]);
          acc[i][5] = fmaf(xs, w1.y, acc[i][5]);
          acc[i][6] = fmaf(xs, w1.z, acc[i][6]);
          acc[i][7] = fmaf(xs, w1.w, acc[i][7]);
        }
      }
    }
    __syncthreads();
  }

  const int c0 = cg * 4;
  float4 bv0 = make_float4(0,0,0,0), bv1 = make_float4(0,0,0,0);
  if (BIAS){
    bv0 = *(const float4*)&bias[c0];
    bv1 = *(const float4*)&bias[c0 + 64];
  }
  #pragma unroll
  for (int i = 0; i < 4; i++){
    int r = row0 + r0 + i;
    if (r < n){
      float4 o0 = make_float4(acc[i][0] + bv0.x, acc[i][1] + bv0.y,
                              acc[i][2] + bv0.z, acc[i][3] + bv0.w);
      float4 o1 = make_float4(acc[i][4] + bv1.x, acc[i][5] + bv1.y,
                              acc[i][6] + bv1.z, acc[i][7] + bv1.w);
      if (OUT_BF16){
        ushort* C = (ushort*)Cv;
        uint2 p0, p1;
        p0.x = f2bf(o0.x) | (f2bf(o0.y) << 16);
        p0.y = f2bf(o0.z) | (f2bf(o0.w) << 16);
        p1.x = f2bf(o1.x) | (f2bf(o1.y) << 16);
        p1.y = f2bf(o1.z) | (f2bf(o1.w) << 16);
        *(uint2*)&C[(size_t)r * HFEAT + c0]      = p0;
        *(uint2*)&C[(size_t)r * HFEAT + c0 + 64] = p1;
      } else {
        float* C = (float*)Cv;
        *(float4*)&C[(size_t)r * HFEAT + c0]      = o0;
        *(float4*)&C[(size_t)r * HFEAT + c0 + 64] = o1;
      }
    }
  }
}

// ---------------- Aggregation: out = A_norm @ in (bf16 gather table) ----------------
// Quarter-wave (16 lanes x uint4 = 256B) per edge row; 4 edges/iter, unroll 2.
// r5 lesson: traffic-bound (8 XCD L2 compulsory re-fetch) -> bf16 halves bytes.

template<int RELU, bool OUT_BF16>
__global__ void __launch_bounds__(256) k_agg(const ushort* __restrict__ in,
                                             const float* __restrict__ bias,
                                             const int* __restrict__ rowoff,
                                             const int2* __restrict__ csr,
                                             const float* __restrict__ dinv,
                                             void* __restrict__ out, int n){
  int gid  = blockIdx.x*blockDim.x + threadIdx.x;
  int node = gid >> 6;
  int lane = gid & 63;
  if (node >= n) return;
  const int w  = lane >> 4;
  const int q  = lane & 15;
  const int f0 = q * 8;

  float acc[8] = {0,0,0,0,0,0,0,0};

  const int e0 = rowoff[node], e1 = rowoff[node+1];
  #pragma unroll 2
  for (int e = e0 + w; e < e1; e += 4){
    int2 c = csr[e];
    uint4 v = *(const uint4*)(in + ((size_t)c.x << 7) + f0);
    float wv = __int_as_float(c.y);
    acc[0] = fmaf(bflo(v.x), wv, acc[0]);
    acc[1] = fmaf(bfhi(v.x), wv, acc[1]);
    acc[2] = fmaf(bflo(v.y), wv, acc[2]);
    acc[3] = fmaf(bfhi(v.y), wv, acc[3]);
    acc[4] = fmaf(bflo(v.z), wv, acc[4]);
    acc[5] = fmaf(bfhi(v.z), wv, acc[5]);
    acc[6] = fmaf(bflo(v.w), wv, acc[6]);
    acc[7] = fmaf(bfhi(v.w), wv, acc[7]);
  }
  if (w == 0){   // self-loop
    float di = dinv[node];
    float sw = di * di;
    uint4 v = *(const uint4*)(in + ((size_t)node << 7) + f0);
    acc[0] = fmaf(bflo(v.x), sw, acc[0]);
    acc[1] = fmaf(bfhi(v.x), sw, acc[1]);
    acc[2] = fmaf(bflo(v.y), sw, acc[2]);
    acc[3] = fmaf(bfhi(v.y), sw, acc[3]);
    acc[4] = fmaf(bflo(v.z), sw, acc[4]);
    acc[5] = fmaf(bfhi(v.z), sw, acc[5]);
    acc[6] = fmaf(bflo(v.w), sw, acc[6]);
    acc[7] = fmaf(bfhi(v.w), sw, acc[7]);
  }
  #pragma unroll
  for (int j = 0; j < 8; j++){
    acc[j] += __shfl_xor(acc[j], 16);
    acc[j] += __shfl_xor(acc[j], 32);
  }

  if (RELU){
    float4 b0 = *(const float4*)&bias[f0];
    float4 b1 = *(const float4*)&bias[f0 + 4];
    acc[0] = fmaxf(acc[0] + b0.x, 0.f);
    acc[1] = fmaxf(acc[1] + b0.y, 0.f);
    acc[2] = fmaxf(acc[2] + b0.z, 0.f);
    acc[3] = fmaxf(acc[3] + b0.w, 0.f);
    acc[4] = fmaxf(acc[4] + b1.x, 0.f);
    acc[5] = fmaxf(acc[5] + b1.y, 0.f);
    acc[6] = fmaxf(acc[6] + b1.z, 0.f);
    acc[7] = fmaxf(acc[7] + b1.w, 0.f);
  }

  if (w == 0){
    if (OUT_BF16){
      uint4 p;
      p.x = f2bf(acc[0]) | (f2bf(acc[1]) << 16);
      p.y = f2bf(acc[2]) | (f2bf(acc[3]) << 16);
      p.z = f2bf(acc[4]) | (f2bf(acc[5]) << 16);
      p.w = f2bf(acc[6]) | (f2bf(acc[7]) << 16);
      *(uint4*)((ushort*)out + ((size_t)node << 7) + f0) = p;
    } else {
      float* o = (float*)out + ((size_t)node << 7) + f0;
      *(float4*)o       = make_float4(acc[0], acc[1], acc[2], acc[3]);
      *(float4*)(o + 4) = make_float4(acc[4], acc[5], acc[6], acc[7]);
    }
  }
}

// ---------------- launch ----------------

extern "C" void kernel_launch(void* const* d_in, const int* in_sizes, int n_in,
                              void* d_out, int out_size, void* d_ws, size_t ws_size,
                              hipStream_t stream){
  const float* x   = (const float*)d_in[0];
  const int*   ei  = (const int*)  d_in[1];
  const float* W1  = (const float*)d_in[2];
  const float* b1  = (const float*)d_in[3];
  const float* Wmu = (const float*)d_in[4];
  const float* bmu = (const float*)d_in[5];
  const float* Wls = (const float*)d_in[6];
  const float* bls = (const float*)d_in[7];
  int N = in_sizes[0] / CIN;
  int E = in_sizes[1] / 2;
  const int* src = ei;
  const int* dst = ei + E;
  float* out = (float*)d_out;

  char* w = (char*)d_ws;
  auto alloc = [&](size_t bytes)->char*{
    char* p = w; w += (bytes + 255) & ~(size_t)255; return p;
  };
  ushort* hW1b  = (ushort*)alloc((size_t)N*HFEAT*2);  // bf16 gemm1 out (gather table 1)
  ushort* hb    = (ushort*)alloc((size_t)N*HFEAT*2);  // bf16 h (gather table 2)
  float*  g     = (float*) alloc((size_t)N*HFEAT*4);  // fp32 agg2 out
  ushort* W1bt  = (ushort*)alloc((size_t)HFEAT*CIN*2);// bf16 W1 transposed [128][256]
  int*   counts = (int*)   alloc((size_t)N*4);
  float* dinv   = (float*) alloc((size_t)N*4);
  int*   rowoff = (int*)   alloc(((size_t)N+1)*4);
  int*   cursor = (int*)   alloc((size_t)N*4);
  int*   bsum   = (int*)   alloc(256*4);
  int2*  csr    = (int2*)  alloc((size_t)E*8);

  int nbN  = (N + 255) / 256;
  int nbE  = (E + 255) / 256;
  int nbS  = (N + 1023) / 1024;
  int nbG  = (N + 63) / 64;

  k_zero_i32<<<nbN, 256, 0, stream>>>(counts, N);
  k_count   <<<nbE, 256, 0, stream>>>(dst, E, counts);
  k_dinv    <<<nbN, 256, 0, stream>>>(counts, N, dinv);
  k_scan1   <<<nbS, 1024, 0, stream>>>(counts, N, rowoff, bsum);
  k_scan2   <<<1, 64, 0, stream>>>(bsum, nbS);
  k_scan3   <<<nbS, 1024, 0, stream>>>(bsum, N, E, rowoff, cursor);
  k_fill    <<<nbE, 256, 0, stream>>>(src, dst, E, dinv, cursor, csr);
  k_cvt_wt  <<<HFEAT, CIN, 0, stream>>>(W1, W1bt);

  k_gemm1_mfma<<<nbG, 256, 0, stream>>>(x, W1bt, hW1b, N);
  int aggBlocks = (int)(((size_t)N*64 + 255) / 256);
  k_agg<1, true ><<<aggBlocks, 256, 0, stream>>>(hW1b, b1, rowoff, csr, dinv, hb, N);
  k_agg<0, false><<<aggBlocks, 256, 0, stream>>>(hb, nullptr, rowoff, csr, dinv, g, N);
  k_gemm<HFEAT, true, false><<<dim3(nbG, 2), 256, 0, stream>>>(
      g, Wmu, Wls, bmu, bls, out, out + (size_t)N*HFEAT, N);
}

// Round 8
// 298.566 us; speedup vs baseline: 16.4688x; 1.0904x over previous
//
#include <hip/hip_runtime.h>
#include <hip/hip_bf16.h>
#include <cstdint>

#define HFEAT 128
#define CIN   256

typedef unsigned int  uint;
typedef unsigned short ushort;
typedef short bf16x8 __attribute__((ext_vector_type(8)));
typedef float f32x4  __attribute__((ext_vector_type(4)));

__device__ inline float bflo(uint u){ return __uint_as_float(u << 16); }
__device__ inline float bfhi(uint u){ return __uint_as_float(u & 0xffff0000u); }
__device__ inline uint  f2bf(float f){
  union { __hip_bfloat16 b; ushort u; } cvt;
  cvt.b = __float2bfloat16(f);   // RNE
  return (uint)cvt.u;
}

// ---------------- CSR build ----------------

__global__ void k_zero_i32(int* __restrict__ p, int n){
  int i = blockIdx.x*blockDim.x + threadIdx.x;
  if (i < n) p[i] = 0;
}

__global__ void k_count(const int* __restrict__ dst, int E, int* __restrict__ counts){
  int e = blockIdx.x*blockDim.x + threadIdx.x;
  if (e < E) atomicAdd(&counts[dst[e]], 1);
}

__global__ void k_dinv(const int* __restrict__ counts, int n, float* __restrict__ dinv){
  int i = blockIdx.x*blockDim.x + threadIdx.x;
  if (i < n) dinv[i] = rsqrtf((float)counts[i] + 1.0f);
}

__global__ void k_scan1(const int* __restrict__ counts, int n,
                        int* __restrict__ excl, int* __restrict__ bsum){
  __shared__ int sm[1024];
  int t = threadIdx.x;
  int i = blockIdx.x*1024 + t;
  int v = (i < n) ? counts[i] : 0;
  sm[t] = v;
  __syncthreads();
  for (int off = 1; off < 1024; off <<= 1){
    int add = (t >= off) ? sm[t-off] : 0;
    __syncthreads();
    sm[t] += add;
    __syncthreads();
  }
  if (i < n) excl[i] = sm[t] - v;
  if (t == 1023) bsum[blockIdx.x] = sm[t];
}

__global__ void k_scan2(int* __restrict__ bsum, int nb){
  if (threadIdx.x == 0 && blockIdx.x == 0){
    int run = 0;
    for (int b = 0; b < nb; b++){ int v = bsum[b]; bsum[b] = run; run += v; }
  }
}

__global__ void k_scan3(const int* __restrict__ bsum, int n, int E,
                        int* __restrict__ rowoff, int* __restrict__ cursor){
  int i = blockIdx.x*blockDim.x + threadIdx.x;   // blockDim == 1024
  if (i < n){
    int v = rowoff[i] + bsum[blockIdx.x];
    rowoff[i] = v;
    cursor[i] = v;
  }
  if (i == 0) rowoff[n] = E;
}

__global__ void k_fill(const int* __restrict__ src, const int* __restrict__ dst, int E,
                       const float* __restrict__ dinv, int* __restrict__ cursor,
                       int2* __restrict__ csr){
  int e = blockIdx.x*blockDim.x + threadIdx.x;
  if (e < E){
    int s = src[e], d = dst[e];
    int pos = atomicAdd(&cursor[d], 1);
    csr[pos] = make_int2(s, __float_as_int(dinv[s]*dinv[d]));
  }
}

// -------- W fp32 [K][H=128] -> bf16 TRANSPOSED [128][K] --------

template<int K>
__global__ void k_cvt_wt(const float* __restrict__ W, ushort* __restrict__ Wt){
  int n = blockIdx.x;          // 128 blocks = output row (col of W)
  int k = threadIdx.x;         // K threads  = output col (row of W)
  Wt[n * K + k] = (ushort)f2bf(W[(size_t)k * HFEAT + n]);
}

// ---------------- Unified bf16-MFMA GEMM ----------------
// out[N,128] = A[N,K] @ W  (W pre-transposed bf16 [128][K]).
// 64x128 tile / 256-thread block (4 waves); wave w -> rows 16w..16w+15.
// K_TILE=64 in LDS; A cvt fp32->bf16 on stage if !IN_BF16 (padded [64][72]
// -> frag reads 2-way banks = free). A/B share the same lane-k map (any
// k-permutation cancels); C/D layout per guide m89: col=lane&15,
// row=(lane>>4)*4+reg. blockIdx.y picks (Wt,bias,out) pair: gemm2 mu/ls.

template<int K, bool IN_BF16, bool BIAS, bool OUT_BF16>
__global__ void __launch_bounds__(256) k_gemm_mfma(const void* __restrict__ Ain,
                                                   const ushort* __restrict__ Wta,
                                                   const ushort* __restrict__ Wtb,
                                                   const float* __restrict__ ba,
                                                   const float* __restrict__ bb,
                                                   void* __restrict__ outa,
                                                   void* __restrict__ outb,
                                                   int n){
  __shared__ ushort Abuf[64][72];
  __shared__ ushort Bbuf[128][72];

  const ushort* Wt   = (blockIdx.y == 0) ? Wta : Wtb;
  const float*  bias = (blockIdx.y == 0) ? ba  : bb;
  void*         outv = (blockIdx.y == 0) ? outa : outb;

  const int tid  = threadIdx.x;
  const int w    = tid >> 6;
  const int l    = tid & 63;
  const int l15  = l & 15;
  const int lhi  = l >> 4;          // 0..3
  const int row0 = blockIdx.x * 64;

  // A staging map: thread -> (row, 16-elem chunk)
  const int ar = tid >> 2;          // 0..63
  const int aq = tid & 3;           // 0..3
  int arow = row0 + ar; if (arow >= n) arow = n - 1;

  f32x4 acc[8];
  #pragma unroll
  for (int t = 0; t < 8; t++) acc[t] = (f32x4){0.f, 0.f, 0.f, 0.f};

  const int NT = K / 64;
  #pragma unroll
  for (int kt = 0; kt < NT; ++kt){
    // stage A: 64 rows x 64 k
    if (IN_BF16){
      const ushort* ap = (const ushort*)Ain + (size_t)arow * K + aq * 16 + kt * 64;
      uint4 v0 = *(const uint4*)(ap);
      uint4 v1 = *(const uint4*)(ap + 8);
      *(uint4*)&Abuf[ar][aq * 16]     = v0;
      *(uint4*)&Abuf[ar][aq * 16 + 8] = v1;
    } else {
      const float* p = (const float*)Ain + (size_t)arow * K + aq * 16 + kt * 64;
      float4 v0 = *(const float4*)(p);
      float4 v1 = *(const float4*)(p + 4);
      float4 v2 = *(const float4*)(p + 8);
      float4 v3 = *(const float4*)(p + 12);
      uint4 pa, pb;
      pa.x = f2bf(v0.x) | (f2bf(v0.y) << 16);
      pa.y = f2bf(v0.z) | (f2bf(v0.w) << 16);
      pa.z = f2bf(v1.x) | (f2bf(v1.y) << 16);
      pa.w = f2bf(v1.z) | (f2bf(v1.w) << 16);
      pb.x = f2bf(v2.x) | (f2bf(v2.y) << 16);
      pb.y = f2bf(v2.z) | (f2bf(v2.w) << 16);
      pb.z = f2bf(v3.x) | (f2bf(v3.y) << 16);
      pb.w = f2bf(v3.z) | (f2bf(v3.w) << 16);
      *(uint4*)&Abuf[ar][aq * 16]     = pa;
      *(uint4*)&Abuf[ar][aq * 16 + 8] = pb;
    }
    // stage B: 128 n x 64 k (bf16 copy)
    #pragma unroll
    for (int j = 0; j < 4; ++j){
      int flat = tid + 256 * j;          // 0..1023
      int bn = flat >> 3;
      int bk = (flat & 7) * 8;
      uint4 v = *(const uint4*)(Wt + (size_t)bn * K + kt * 64 + bk);
      *(uint4*)&Bbuf[bn][bk] = v;
    }
    __syncthreads();

    #pragma unroll
    for (int ks = 0; ks < 2; ++ks){
      const int ko = ks * 32 + lhi * 8;
      bf16x8 af = *(bf16x8*)&Abuf[16 * w + l15][ko];
      #pragma unroll
      for (int nt = 0; nt < 8; ++nt){
        bf16x8 bf = *(bf16x8*)&Bbuf[nt * 16 + l15][ko];
        acc[nt] = __builtin_amdgcn_mfma_f32_16x16x32_bf16(af, bf, acc[nt], 0, 0, 0);
      }
    }
    __syncthreads();
  }

  // epilogue: row = row0 + 16w + lhi*4 + j, col = nt*16 + l15
  float bv[8];
  #pragma unroll
  for (int nt = 0; nt < 8; ++nt) bv[nt] = BIAS ? bias[nt * 16 + l15] : 0.f;

  #pragma unroll
  for (int j = 0; j < 4; ++j){
    int r = row0 + 16 * w + lhi * 4 + j;
    if (r < n){
      if (OUT_BF16){
        ushort* orow = (ushort*)outv + (size_t)r * HFEAT + l15;
        #pragma unroll
        for (int nt = 0; nt < 8; ++nt)
          orow[nt * 16] = (ushort)f2bf(acc[nt][j] + bv[nt]);
      } else {
        float* orow = (float*)outv + (size_t)r * HFEAT + l15;
        #pragma unroll
        for (int nt = 0; nt < 8; ++nt)
          orow[nt * 16] = acc[nt][j] + bv[nt];
      }
    }
  }
}

// ---------------- Aggregation: out = A_norm @ in (bf16 gather table) ----------------
// Quarter-wave (16 lanes x uint4 = 256B) per edge row; 4 edges/iter, unroll 2.
// r5 lesson: traffic-bound (8 XCD L2 compulsory re-fetch) -> bf16 halves bytes.

template<int RELU, bool OUT_BF16>
__global__ void __launch_bounds__(256) k_agg(const ushort* __restrict__ in,
                                             const float* __restrict__ bias,
                                             const int* __restrict__ rowoff,
                                             const int2* __restrict__ csr,
                                             const float* __restrict__ dinv,
                                             void* __restrict__ out, int n){
  int gid  = blockIdx.x*blockDim.x + threadIdx.x;
  int node = gid >> 6;
  int lane = gid & 63;
  if (node >= n) return;
  const int w  = lane >> 4;
  const int q  = lane & 15;
  const int f0 = q * 8;

  float acc[8] = {0,0,0,0,0,0,0,0};

  const int e0 = rowoff[node], e1 = rowoff[node+1];
  #pragma unroll 2
  for (int e = e0 + w; e < e1; e += 4){
    int2 c = csr[e];
    uint4 v = *(const uint4*)(in + ((size_t)c.x << 7) + f0);
    float wv = __int_as_float(c.y);
    acc[0] = fmaf(bflo(v.x), wv, acc[0]);
    acc[1] = fmaf(bfhi(v.x), wv, acc[1]);
    acc[2] = fmaf(bflo(v.y), wv, acc[2]);
    acc[3] = fmaf(bfhi(v.y), wv, acc[3]);
    acc[4] = fmaf(bflo(v.z), wv, acc[4]);
    acc[5] = fmaf(bfhi(v.z), wv, acc[5]);
    acc[6] = fmaf(bflo(v.w), wv, acc[6]);
    acc[7] = fmaf(bfhi(v.w), wv, acc[7]);
  }
  if (w == 0){   // self-loop
    float di = dinv[node];
    float sw = di * di;
    uint4 v = *(const uint4*)(in + ((size_t)node << 7) + f0);
    acc[0] = fmaf(bflo(v.x), sw, acc[0]);
    acc[1] = fmaf(bfhi(v.x), sw, acc[1]);
    acc[2] = fmaf(bflo(v.y), sw, acc[2]);
    acc[3] = fmaf(bfhi(v.y), sw, acc[3]);
    acc[4] = fmaf(bflo(v.z), sw, acc[4]);
    acc[5] = fmaf(bfhi(v.z), sw, acc[5]);
    acc[6] = fmaf(bflo(v.w), sw, acc[6]);
    acc[7] = fmaf(bfhi(v.w), sw, acc[7]);
  }
  #pragma unroll
  for (int j = 0; j < 8; j++){
    acc[j] += __shfl_xor(acc[j], 16);
    acc[j] += __shfl_xor(acc[j], 32);
  }

  if (RELU){
    float4 b0 = *(const float4*)&bias[f0];
    float4 b1 = *(const float4*)&bias[f0 + 4];
    acc[0] = fmaxf(acc[0] + b0.x, 0.f);
    acc[1] = fmaxf(acc[1] + b0.y, 0.f);
    acc[2] = fmaxf(acc[2] + b0.z, 0.f);
    acc[3] = fmaxf(acc[3] + b0.w, 0.f);
    acc[4] = fmaxf(acc[4] + b1.x, 0.f);
    acc[5] = fmaxf(acc[5] + b1.y, 0.f);
    acc[6] = fmaxf(acc[6] + b1.z, 0.f);
    acc[7] = fmaxf(acc[7] + b1.w, 0.f);
  }

  if (w == 0){
    if (OUT_BF16){
      uint4 p;
      p.x = f2bf(acc[0]) | (f2bf(acc[1]) << 16);
      p.y = f2bf(acc[2]) | (f2bf(acc[3]) << 16);
      p.z = f2bf(acc[4]) | (f2bf(acc[5]) << 16);
      p.w = f2bf(acc[6]) | (f2bf(acc[7]) << 16);
      *(uint4*)((ushort*)out + ((size_t)node << 7) + f0) = p;
    } else {
      float* o = (float*)out + ((size_t)node << 7) + f0;
      *(float4*)o       = make_float4(acc[0], acc[1], acc[2], acc[3]);
      *(float4*)(o + 4) = make_float4(acc[4], acc[5], acc[6], acc[7]);
    }
  }
}

// ---------------- launch ----------------

extern "C" void kernel_launch(void* const* d_in, const int* in_sizes, int n_in,
                              void* d_out, int out_size, void* d_ws, size_t ws_size,
                              hipStream_t stream){
  const float* x   = (const float*)d_in[0];
  const int*   ei  = (const int*)  d_in[1];
  const float* W1  = (const float*)d_in[2];
  const float* b1  = (const float*)d_in[3];
  const float* Wmu = (const float*)d_in[4];
  const float* bmu = (const float*)d_in[5];
  const float* Wls = (const float*)d_in[6];
  const float* bls = (const float*)d_in[7];
  int N = in_sizes[0] / CIN;
  int E = in_sizes[1] / 2;
  const int* src = ei;
  const int* dst = ei + E;
  float* out = (float*)d_out;

  char* w = (char*)d_ws;
  auto alloc = [&](size_t bytes)->char*{
    char* p = w; w += (bytes + 255) & ~(size_t)255; return p;
  };
  ushort* hW1b  = (ushort*)alloc((size_t)N*HFEAT*2);  // bf16 gemm1 out (gather table 1)
  ushort* hb    = (ushort*)alloc((size_t)N*HFEAT*2);  // bf16 h (gather table 2)
  ushort* gb    = (ushort*)alloc((size_t)N*HFEAT*2);  // bf16 agg2 out (gemm2 input)
  ushort* W1bt  = (ushort*)alloc((size_t)HFEAT*CIN*2);  // bf16 W1^T  [128][256]
  ushort* Wmut  = (ushort*)alloc((size_t)HFEAT*HFEAT*2);// bf16 Wmu^T [128][128]
  ushort* Wlst  = (ushort*)alloc((size_t)HFEAT*HFEAT*2);// bf16 Wls^T [128][128]
  int*   counts = (int*)   alloc((size_t)N*4);
  float* dinv   = (float*) alloc((size_t)N*4);
  int*   rowoff = (int*)   alloc(((size_t)N+1)*4);
  int*   cursor = (int*)   alloc((size_t)N*4);
  int*   bsum   = (int*)   alloc(256*4);
  int2*  csr    = (int2*)  alloc((size_t)E*8);

  int nbN  = (N + 255) / 256;
  int nbE  = (E + 255) / 256;
  int nbS  = (N + 1023) / 1024;
  int nbG  = (N + 63) / 64;

  k_zero_i32<<<nbN, 256, 0, stream>>>(counts, N);
  k_count   <<<nbE, 256, 0, stream>>>(dst, E, counts);
  k_dinv    <<<nbN, 256, 0, stream>>>(counts, N, dinv);
  k_scan1   <<<nbS, 1024, 0, stream>>>(counts, N, rowoff, bsum);
  k_scan2   <<<1, 64, 0, stream>>>(bsum, nbS);
  k_scan3   <<<nbS, 1024, 0, stream>>>(bsum, N, E, rowoff, cursor);
  k_fill    <<<nbE, 256, 0, stream>>>(src, dst, E, dinv, cursor, csr);
  k_cvt_wt<CIN>  <<<HFEAT, CIN,   0, stream>>>(W1,  W1bt);
  k_cvt_wt<HFEAT><<<HFEAT, HFEAT, 0, stream>>>(Wmu, Wmut);
  k_cvt_wt<HFEAT><<<HFEAT, HFEAT, 0, stream>>>(Wls, Wlst);

  k_gemm_mfma<CIN, false, false, true><<<dim3(nbG, 1), 256, 0, stream>>>(
      x, W1bt, W1bt, nullptr, nullptr, hW1b, hW1b, N);
  int aggBlocks = (int)(((size_t)N*64 + 255) / 256);
  k_agg<1, true><<<aggBlocks, 256, 0, stream>>>(hW1b, b1, rowoff, csr, dinv, hb, N);
  k_agg<0, true><<<aggBlocks, 256, 0, stream>>>(hb, nullptr, rowoff, csr, dinv, gb, N);
  k_gemm_mfma<HFEAT, true, true, false><<<dim3(nbG, 2), 256, 0, stream>>>(
      gb, Wmut, Wlst, bmu, bls, out, out + (size_t)N*HFEAT, N);
}

// Round 9
// 295.264 us; speedup vs baseline: 16.6530x; 1.0112x over previous
//
#include <hip/hip_runtime.h>
#include <hip/hip_bf16.h>
#include <cstdint>

#define HFEAT 128
#define CIN   256

typedef unsigned int  uint;
typedef unsigned short ushort;
typedef short bf16x8 __attribute__((ext_vector_type(8)));
typedef float f32x4  __attribute__((ext_vector_type(4)));

__device__ inline float bflo(uint u){ return __uint_as_float(u << 16); }
__device__ inline float bfhi(uint u){ return __uint_as_float(u & 0xffff0000u); }
__device__ inline uint  f2bf(float f){
  union { __hip_bfloat16 b; ushort u; } cvt;
  cvt.b = __float2bfloat16(f);   // RNE
  return (uint)cvt.u;
}

// ---------------- CSR build ----------------

__global__ void k_count(const int* __restrict__ dst, int E, int* __restrict__ counts){
  int e = blockIdx.x*blockDim.x + threadIdx.x;
  if (e < E) atomicAdd(&counts[dst[e]], 1);
}

// scan1 + dinv fused: per-1024 block inclusive scan; dinv[i]=rsqrt(count+1)
__global__ void k_scan1(const int* __restrict__ counts, int n,
                        int* __restrict__ excl, int* __restrict__ bsum,
                        float* __restrict__ dinv){
  __shared__ int sm[1024];
  int t = threadIdx.x;
  int i = blockIdx.x*1024 + t;
  int v = (i < n) ? counts[i] : 0;
  if (i < n) dinv[i] = rsqrtf((float)v + 1.0f);
  sm[t] = v;
  __syncthreads();
  for (int off = 1; off < 1024; off <<= 1){
    int add = (t >= off) ? sm[t-off] : 0;
    __syncthreads();
    sm[t] += add;
    __syncthreads();
  }
  if (i < n) excl[i] = sm[t] - v;
  if (t == 1023) bsum[blockIdx.x] = sm[t];
}

__global__ void k_scan2(int* __restrict__ bsum, int nb){
  if (threadIdx.x == 0 && blockIdx.x == 0){
    int run = 0;
    for (int b = 0; b < nb; b++){ int v = bsum[b]; bsum[b] = run; run += v; }
  }
}

__global__ void k_scan3(const int* __restrict__ bsum, int n, int E,
                        int* __restrict__ rowoff, int* __restrict__ cursor){
  int i = blockIdx.x*blockDim.x + threadIdx.x;   // blockDim == 1024
  if (i < n){
    int v = rowoff[i] + bsum[blockIdx.x];
    rowoff[i] = v;
    cursor[i] = v;
  }
  if (i == 0) rowoff[n] = E;
}

// weightless fill: 4B/edge (r8 lesson: scatter writeback = footprint x 8 XCDs;
// halving the footprint halves the 8-way partial-line writeback)
__global__ void k_fill(const int* __restrict__ src, const int* __restrict__ dst, int E,
                       int* __restrict__ cursor, int* __restrict__ csr4){
  int e = blockIdx.x*blockDim.x + threadIdx.x;
  if (e < E){
    int pos = atomicAdd(&cursor[dst[e]], 1);
    csr4[pos] = src[e];
  }
}

// -------- all three W fp32 [K][128] -> bf16 TRANSPOSED [128][K], one kernel --------

__global__ void k_cvt_all(const float* __restrict__ W1,  const float* __restrict__ Wmu,
                          const float* __restrict__ Wls, ushort* __restrict__ W1t,
                          ushort* __restrict__ Wmut, ushort* __restrict__ Wlst){
  int b = blockIdx.x, t = threadIdx.x;            // 384 blocks x 256 threads
  if (b < 128){
    W1t[b * CIN + t] = (ushort)f2bf(W1[(size_t)t * HFEAT + b]);
  } else if (b < 256){
    int nn = b - 128;
    if (t < HFEAT) Wmut[nn * HFEAT + t] = (ushort)f2bf(Wmu[(size_t)t * HFEAT + nn]);
  } else {
    int nn = b - 256;
    if (t < HFEAT) Wlst[nn * HFEAT + t] = (ushort)f2bf(Wls[(size_t)t * HFEAT + nn]);
  }
}

// ---------------- Unified bf16-MFMA GEMM ----------------
// out[N,128] = A[N,K] @ W (W pre-transposed bf16 [128][K]).
// 64x128 tile / 256-thread block (4 waves). SCALE_DINV multiplies each output
// row by dinv[r] (pre-scaled gather table for the weightless-CSR agg).
// C/D layout per guide m89: col=lane&15, row=(lane>>4)*4+reg.

template<int K, bool IN_BF16, bool BIAS, bool OUT_BF16, bool SCALE_DINV>
__global__ void __launch_bounds__(256) k_gemm_mfma(const void* __restrict__ Ain,
                                                   const ushort* __restrict__ Wta,
                                                   const ushort* __restrict__ Wtb,
                                                   const float* __restrict__ ba,
                                                   const float* __restrict__ bb,
                                                   const float* __restrict__ dinv,
                                                   void* __restrict__ outa,
                                                   void* __restrict__ outb,
                                                   int n){
  __shared__ ushort Abuf[64][72];
  __shared__ ushort Bbuf[128][72];

  const ushort* Wt   = (blockIdx.y == 0) ? Wta : Wtb;
  const float*  bias = (blockIdx.y == 0) ? ba  : bb;
  void*         outv = (blockIdx.y == 0) ? outa : outb;

  const int tid  = threadIdx.x;
  const int w    = tid >> 6;
  const int l    = tid & 63;
  const int l15  = l & 15;
  const int lhi  = l >> 4;          // 0..3
  const int row0 = blockIdx.x * 64;

  const int ar = tid >> 2;          // 0..63
  const int aq = tid & 3;           // 0..3
  int arow = row0 + ar; if (arow >= n) arow = n - 1;

  f32x4 acc[8];
  #pragma unroll
  for (int t = 0; t < 8; t++) acc[t] = (f32x4){0.f, 0.f, 0.f, 0.f};

  const int NT = K / 64;
  #pragma unroll
  for (int kt = 0; kt < NT; ++kt){
    if (IN_BF16){
      const ushort* ap = (const ushort*)Ain + (size_t)arow * K + aq * 16 + kt * 64;
      uint4 v0 = *(const uint4*)(ap);
      uint4 v1 = *(const uint4*)(ap + 8);
      *(uint4*)&Abuf[ar][aq * 16]     = v0;
      *(uint4*)&Abuf[ar][aq * 16 + 8] = v1;
    } else {
      const float* p = (const float*)Ain + (size_t)arow * K + aq * 16 + kt * 64;
      float4 v0 = *(const float4*)(p);
      float4 v1 = *(const float4*)(p + 4);
      float4 v2 = *(const float4*)(p + 8);
      float4 v3 = *(const float4*)(p + 12);
      uint4 pa, pb;
      pa.x = f2bf(v0.x) | (f2bf(v0.y) << 16);
      pa.y = f2bf(v0.z) | (f2bf(v0.w) << 16);
      pa.z = f2bf(v1.x) | (f2bf(v1.y) << 16);
      pa.w = f2bf(v1.z) | (f2bf(v1.w) << 16);
      pb.x = f2bf(v2.x) | (f2bf(v2.y) << 16);
      pb.y = f2bf(v2.z) | (f2bf(v2.w) << 16);
      pb.z = f2bf(v3.x) | (f2bf(v3.y) << 16);
      pb.w = f2bf(v3.z) | (f2bf(v3.w) << 16);
      *(uint4*)&Abuf[ar][aq * 16]     = pa;
      *(uint4*)&Abuf[ar][aq * 16 + 8] = pb;
    }
    #pragma unroll
    for (int j = 0; j < 4; ++j){
      int flat = tid + 256 * j;          // 0..1023
      int bn = flat >> 3;
      int bk = (flat & 7) * 8;
      uint4 v = *(const uint4*)(Wt + (size_t)bn * K + kt * 64 + bk);
      *(uint4*)&Bbuf[bn][bk] = v;
    }
    __syncthreads();

    #pragma unroll
    for (int ks = 0; ks < 2; ++ks){
      const int ko = ks * 32 + lhi * 8;
      bf16x8 af = *(bf16x8*)&Abuf[16 * w + l15][ko];
      #pragma unroll
      for (int nt = 0; nt < 8; ++nt){
        bf16x8 bf = *(bf16x8*)&Bbuf[nt * 16 + l15][ko];
        acc[nt] = __builtin_amdgcn_mfma_f32_16x16x32_bf16(af, bf, acc[nt], 0, 0, 0);
      }
    }
    __syncthreads();
  }

  float bv[8];
  #pragma unroll
  for (int nt = 0; nt < 8; ++nt) bv[nt] = BIAS ? bias[nt * 16 + l15] : 0.f;

  #pragma unroll
  for (int j = 0; j < 4; ++j){
    int r = row0 + 16 * w + lhi * 4 + j;
    if (r < n){
      float sc = SCALE_DINV ? dinv[r] : 1.f;
      if (OUT_BF16){
        ushort* orow = (ushort*)outv + (size_t)r * HFEAT + l15;
        #pragma unroll
        for (int nt = 0; nt < 8; ++nt)
          orow[nt * 16] = (ushort)f2bf((acc[nt][j] + bv[nt]) * sc);
      } else {
        float* orow = (float*)outv + (size_t)r * HFEAT + l15;
        #pragma unroll
        for (int nt = 0; nt < 8; ++nt)
          orow[nt * 16] = acc[nt][j] + bv[nt];
      }
    }
  }
}

// ---------------- Aggregation (weightless CSR, pre-scaled bf16 table) ------------
// table[j] = dinv_j * h_j (bf16). agg_i = dinv_i * (sum_{j in N(i)} table[j] + table[i]).
// RELU=1 (layer1): write bf16( dinv_i * max(agg_i + bias, 0) )  -> next table.
// RELU=0 (layer2): write bf16( agg_i )                          -> g for gemm2.
// Quarter-wave (16 lanes x uint4 = 256B) per edge row; 4 edges/iter, unroll 2.

template<int RELU>
__global__ void __launch_bounds__(256) k_agg(const ushort* __restrict__ in,
                                             const float* __restrict__ bias,
                                             const int* __restrict__ rowoff,
                                             const int* __restrict__ csr4,
                                             const float* __restrict__ dinv,
                                             ushort* __restrict__ out, int n){
  int gid  = blockIdx.x*blockDim.x + threadIdx.x;
  int node = gid >> 6;
  int lane = gid & 63;
  if (node >= n) return;
  const int w  = lane >> 4;
  const int q  = lane & 15;
  const int f0 = q * 8;

  float acc[8] = {0,0,0,0,0,0,0,0};

  const int e0 = rowoff[node], e1 = rowoff[node+1];
  #pragma unroll 2
  for (int e = e0 + w; e < e1; e += 4){
    int s = csr4[e];
    uint4 v = *(const uint4*)(in + ((size_t)s << 7) + f0);
    acc[0] += bflo(v.x); acc[1] += bfhi(v.x);
    acc[2] += bflo(v.y); acc[3] += bfhi(v.y);
    acc[4] += bflo(v.z); acc[5] += bfhi(v.z);
    acc[6] += bflo(v.w); acc[7] += bfhi(v.w);
  }
  if (w == 0){   // self term: table[node], added once
    uint4 v = *(const uint4*)(in + ((size_t)node << 7) + f0);
    acc[0] += bflo(v.x); acc[1] += bfhi(v.x);
    acc[2] += bflo(v.y); acc[3] += bfhi(v.y);
    acc[4] += bflo(v.z); acc[5] += bfhi(v.z);
    acc[6] += bflo(v.w); acc[7] += bfhi(v.w);
  }
  #pragma unroll
  for (int j = 0; j < 8; j++){
    acc[j] += __shfl_xor(acc[j], 16);
    acc[j] += __shfl_xor(acc[j], 32);
  }

  if (w == 0){
    float di = dinv[node];
    uint4 p;
    if (RELU){
      float4 b0 = *(const float4*)&bias[f0];
      float4 b1 = *(const float4*)&bias[f0 + 4];
      float r0 = fmaxf(fmaf(acc[0], di, b0.x), 0.f) * di;
      float r1 = fmaxf(fmaf(acc[1], di, b0.y), 0.f) * di;
      float r2 = fmaxf(fmaf(acc[2], di, b0.z), 0.f) * di;
      float r3 = fmaxf(fmaf(acc[3], di, b0.w), 0.f) * di;
      float r4 = fmaxf(fmaf(acc[4], di, b1.x), 0.f) * di;
      float r5 = fmaxf(fmaf(acc[5], di, b1.y), 0.f) * di;
      float r6 = fmaxf(fmaf(acc[6], di, b1.z), 0.f) * di;
      float r7 = fmaxf(fmaf(acc[7], di, b1.w), 0.f) * di;
      p.x = f2bf(r0) | (f2bf(r1) << 16);
      p.y = f2bf(r2) | (f2bf(r3) << 16);
      p.z = f2bf(r4) | (f2bf(r5) << 16);
      p.w = f2bf(r6) | (f2bf(r7) << 16);
    } else {
      p.x = f2bf(acc[0] * di) | (f2bf(acc[1] * di) << 16);
      p.y = f2bf(acc[2] * di) | (f2bf(acc[3] * di) << 16);
      p.z = f2bf(acc[4] * di) | (f2bf(acc[5] * di) << 16);
      p.w = f2bf(acc[6] * di) | (f2bf(acc[7] * di) << 16);
    }
    *(uint4*)(out + ((size_t)node << 7) + f0) = p;
  }
}

// ---------------- launch ----------------

extern "C" void kernel_launch(void* const* d_in, const int* in_sizes, int n_in,
                              void* d_out, int out_size, void* d_ws, size_t ws_size,
                              hipStream_t stream){
  const float* x   = (const float*)d_in[0];
  const int*   ei  = (const int*)  d_in[1];
  const float* W1  = (const float*)d_in[2];
  const float* b1  = (const float*)d_in[3];
  const float* Wmu = (const float*)d_in[4];
  const float* bmu = (const float*)d_in[5];
  const float* Wls = (const float*)d_in[6];
  const float* bls = (const float*)d_in[7];
  int N = in_sizes[0] / CIN;
  int E = in_sizes[1] / 2;
  const int* src = ei;
  const int* dst = ei + E;
  float* out = (float*)d_out;

  char* w = (char*)d_ws;
  auto alloc = [&](size_t bytes)->char*{
    char* p = w; w += (bytes + 255) & ~(size_t)255; return p;
  };
  ushort* t1    = (ushort*)alloc((size_t)N*HFEAT*2);  // table1 = dinv*(x@W1), bf16
  ushort* t2    = (ushort*)alloc((size_t)N*HFEAT*2);  // table2 = dinv*h, bf16
  ushort* gb    = (ushort*)alloc((size_t)N*HFEAT*2);  // g, bf16 (gemm2 input)
  ushort* W1bt  = (ushort*)alloc((size_t)HFEAT*CIN*2);  // bf16 W1^T  [128][256]
  ushort* Wmut  = (ushort*)alloc((size_t)HFEAT*HFEAT*2);// bf16 Wmu^T [128][128]
  ushort* Wlst  = (ushort*)alloc((size_t)HFEAT*HFEAT*2);// bf16 Wls^T [128][128]
  int*   counts = (int*)   alloc((size_t)N*4);
  float* dinv   = (float*) alloc((size_t)N*4);
  int*   rowoff = (int*)   alloc(((size_t)N+1)*4);
  int*   cursor = (int*)   alloc((size_t)N*4);
  int*   bsum   = (int*)   alloc(256*4);
  int*   csr4   = (int*)   alloc((size_t)E*4);

  int nbE  = (E + 255) / 256;
  int nbS  = (N + 1023) / 1024;
  int nbG  = (N + 63) / 64;

  hipMemsetAsync(counts, 0, (size_t)N*4, stream);
  k_count   <<<nbE, 256, 0, stream>>>(dst, E, counts);
  k_scan1   <<<nbS, 1024, 0, stream>>>(counts, N, rowoff, bsum, dinv);
  k_scan2   <<<1, 64, 0, stream>>>(bsum, nbS);
  k_scan3   <<<nbS, 1024, 0, stream>>>(bsum, N, E, rowoff, cursor);
  k_fill    <<<nbE, 256, 0, stream>>>(src, dst, E, cursor, csr4);
  k_cvt_all <<<384, 256, 0, stream>>>(W1, Wmu, Wls, W1bt, Wmut, Wlst);

  // gemm1: t1 = dinv * (x @ W1), bf16
  k_gemm_mfma<CIN, false, false, true, true><<<dim3(nbG, 1), 256, 0, stream>>>(
      x, W1bt, W1bt, nullptr, nullptr, dinv, t1, t1, N);
  int aggBlocks = (int)(((size_t)N*64 + 255) / 256);
  // agg1: t2 = dinv * relu(dinv*(sum t1) + b1)
  k_agg<1><<<aggBlocks, 256, 0, stream>>>(t1, b1, rowoff, csr4, dinv, t2, N);
  // agg2: gb = dinv * (sum t2)
  k_agg<0><<<aggBlocks, 256, 0, stream>>>(t2, nullptr, rowoff, csr4, dinv, gb, N);
  // gemm2: out = gb @ {Wmu,Wls} + {bmu,bls}, fp32
  k_gemm_mfma<HFEAT, true, true, false, false><<<dim3(nbG, 2), 256, 0, stream>>>(
      gb, Wmut, Wlst, bmu, bls, nullptr, out, out + (size_t)N*HFEAT, N);
}

// Round 10
// 253.089 us; speedup vs baseline: 19.4280x; 1.1666x over previous
//
#include <hip/hip_runtime.h>
#include <hip/hip_bf16.h>
#include <cstdint>

#define HFEAT 128
#define CIN   256

typedef unsigned int  uint;
typedef unsigned short ushort;
typedef short bf16x8 __attribute__((ext_vector_type(8)));
typedef float f32x4  __attribute__((ext_vector_type(4)));

__device__ inline float bflo(uint u){ return __uint_as_float(u << 16); }
__device__ inline float bfhi(uint u){ return __uint_as_float(u & 0xffff0000u); }
__device__ inline uint  f2bf(float f){
  union { __hip_bfloat16 b; ushort u; } cvt;
  cvt.b = __float2bfloat16(f);   // RNE
  return (uint)cvt.u;
}

// ---------------- CSR build (rank-trick: atomics only in count) ----------------

// scan1 + dinv: per-1024-block inclusive scan of counts; dinv[i]=rsqrt(cnt+1)
__global__ void k_scan1(const int* __restrict__ counts, int n,
                        int* __restrict__ excl, int* __restrict__ bsum,
                        float* __restrict__ dinv){
  __shared__ int sm[1024];
  int t = threadIdx.x;
  int i = blockIdx.x*1024 + t;
  int v = (i < n) ? counts[i] : 0;
  if (i < n) dinv[i] = rsqrtf((float)v + 1.0f);
  sm[t] = v;
  __syncthreads();
  for (int off = 1; off < 1024; off <<= 1){
    int add = (t >= off) ? sm[t-off] : 0;
    __syncthreads();
    sm[t] += add;
    __syncthreads();
  }
  if (i < n) excl[i] = sm[t] - v;
  if (t == 1023) bsum[blockIdx.x] = sm[t];
}

// parallel block-sum scan (nb <= 1024); replaces 49 serial global round-trips
__global__ void k_scan2(int* __restrict__ bsum, int nb){
  __shared__ int sm[1024];
  int t = threadIdx.x;
  int v = (t < nb) ? bsum[t] : 0;
  sm[t] = v;
  __syncthreads();
  for (int off = 1; off < 1024; off <<= 1){
    int add = (t >= off) ? sm[t-off] : 0;
    __syncthreads();
    sm[t] += add;
    __syncthreads();
  }
  if (t < nb) bsum[t] = sm[t] - v;   // exclusive
}

__global__ void k_scan3(const int* __restrict__ bsum, int n, int E,
                        int* __restrict__ rowoff){
  int i = blockIdx.x*blockDim.x + threadIdx.x;   // blockDim == 1024
  if (i < n) rowoff[i] += bsum[blockIdx.x];
  if (i == 0) rowoff[n] = E;
}

// no-atomic fill: pos = rowoff[dst] + rank (captured from count's atomicAdd return).
// csr entries are ushort (requires N < 65536; here N=50000).
__global__ void k_fill(const int* __restrict__ src, const int* __restrict__ dst,
                       const int* __restrict__ rank, int E,
                       const int* __restrict__ rowoff, ushort* __restrict__ csr2){
  int e = blockIdx.x*blockDim.x + threadIdx.x;
  if (e < E) csr2[rowoff[dst[e]] + rank[e]] = (ushort)src[e];
}

// -------- all three W fp32 [K][128] -> bf16 TRANSPOSED [128][K], one kernel --------

__global__ void k_cvt_all(const float* __restrict__ W1,  const float* __restrict__ Wmu,
                          const float* __restrict__ Wls, ushort* __restrict__ W1t,
                          ushort* __restrict__ Wmut, ushort* __restrict__ Wlst){
  int b = blockIdx.x, t = threadIdx.x;            // 384 blocks x 256 threads
  if (b < 128){
    W1t[b * CIN + t] = (ushort)f2bf(W1[(size_t)t * HFEAT + b]);
  } else if (b < 256){
    int nn = b - 128;
    if (t < HFEAT) Wmut[nn * HFEAT + t] = (ushort)f2bf(Wmu[(size_t)t * HFEAT + nn]);
  } else {
    int nn = b - 256;
    if (t < HFEAT) Wlst[nn * HFEAT + t] = (ushort)f2bf(Wls[(size_t)t * HFEAT + nn]);
  }
}

// ---------------- bf16-MFMA GEMM body (device fn) ----------------
// out[N,128] = A[N,K] @ W (W pre-transposed bf16 [128][K]).
// 64x128 tile / 256-thread block (4 waves). C/D layout per guide m89:
// col=lane&15, row=(lane>>4)*4+reg.

template<int K, bool IN_BF16, bool BIAS, bool OUT_BF16>
__device__ __forceinline__ void gemm_body(int bid,
                                          const void* __restrict__ Ain,
                                          const ushort* __restrict__ Wt,
                                          const float* __restrict__ bias,
                                          void* __restrict__ outv,
                                          int n,
                                          ushort (*Abuf)[72], ushort (*Bbuf)[72]){
  const int tid  = threadIdx.x;
  const int w    = tid >> 6;
  const int l    = tid & 63;
  const int l15  = l & 15;
  const int lhi  = l >> 4;          // 0..3
  const int row0 = bid * 64;

  const int ar = tid >> 2;          // 0..63
  const int aq = tid & 3;           // 0..3
  int arow = row0 + ar; if (arow >= n) arow = n - 1;

  f32x4 acc[8];
  #pragma unroll
  for (int t = 0; t < 8; t++) acc[t] = (f32x4){0.f, 0.f, 0.f, 0.f};

  const int NT = K / 64;
  #pragma unroll
  for (int kt = 0; kt < NT; ++kt){
    if (IN_BF16){
      const ushort* ap = (const ushort*)Ain + (size_t)arow * K + aq * 16 + kt * 64;
      uint4 v0 = *(const uint4*)(ap);
      uint4 v1 = *(const uint4*)(ap + 8);
      *(uint4*)&Abuf[ar][aq * 16]     = v0;
      *(uint4*)&Abuf[ar][aq * 16 + 8] = v1;
    } else {
      const float* p = (const float*)Ain + (size_t)arow * K + aq * 16 + kt * 64;
      float4 v0 = *(const float4*)(p);
      float4 v1 = *(const float4*)(p + 4);
      float4 v2 = *(const float4*)(p + 8);
      float4 v3 = *(const float4*)(p + 12);
      uint4 pa, pb;
      pa.x = f2bf(v0.x) | (f2bf(v0.y) << 16);
      pa.y = f2bf(v0.z) | (f2bf(v0.w) << 16);
      pa.z = f2bf(v1.x) | (f2bf(v1.y) << 16);
      pa.w = f2bf(v1.z) | (f2bf(v1.w) << 16);
      pb.x = f2bf(v2.x) | (f2bf(v2.y) << 16);
      pb.y = f2bf(v2.z) | (f2bf(v2.w) << 16);
      pb.z = f2bf(v3.x) | (f2bf(v3.y) << 16);
      pb.w = f2bf(v3.z) | (f2bf(v3.w) << 16);
      *(uint4*)&Abuf[ar][aq * 16]     = pa;
      *(uint4*)&Abuf[ar][aq * 16 + 8] = pb;
    }
    #pragma unroll
    for (int j = 0; j < 4; ++j){
      int flat = tid + 256 * j;          // 0..1023
      int bn = flat >> 3;
      int bk = (flat & 7) * 8;
      uint4 v = *(const uint4*)(Wt + (size_t)bn * K + kt * 64 + bk);
      *(uint4*)&Bbuf[bn][bk] = v;
    }
    __syncthreads();

    #pragma unroll
    for (int ks = 0; ks < 2; ++ks){
      const int ko = ks * 32 + lhi * 8;
      bf16x8 af = *(bf16x8*)&Abuf[16 * w + l15][ko];
      #pragma unroll
      for (int nt = 0; nt < 8; ++nt){
        bf16x8 bf = *(bf16x8*)&Bbuf[nt * 16 + l15][ko];
        acc[nt] = __builtin_amdgcn_mfma_f32_16x16x32_bf16(af, bf, acc[nt], 0, 0, 0);
      }
    }
    __syncthreads();
  }

  float bv[8];
  #pragma unroll
  for (int nt = 0; nt < 8; ++nt) bv[nt] = BIAS ? bias[nt * 16 + l15] : 0.f;

  #pragma unroll
  for (int j = 0; j < 4; ++j){
    int r = row0 + 16 * w + lhi * 4 + j;
    if (r < n){
      if (OUT_BF16){
        ushort* orow = (ushort*)outv + (size_t)r * HFEAT + l15;
        #pragma unroll
        for (int nt = 0; nt < 8; ++nt)
          orow[nt * 16] = (ushort)f2bf(acc[nt][j] + bv[nt]);
      } else {
        float* orow = (float*)outv + (size_t)r * HFEAT + l15;
        #pragma unroll
        for (int nt = 0; nt < 8; ++nt)
          orow[nt * 16] = acc[nt][j] + bv[nt];
      }
    }
  }
}

// ---------------- fused: edge-count (+rank capture) || gemm1 ----------------
// Count blocks [0,nbE) run the 800k memory-side atomics while gemm blocks
// [nbE, nbE+nbG) keep the MFMA/LDS pipes busy -> count latency hidden.
// gemm1 output t1 = bf16(x@W1) UNSCALED (dinv applied at agg gather), so
// gemm1 has no dependency on the CSR/degree chain.

__global__ void __launch_bounds__(256) k_count_gemm1(const int* __restrict__ dst, int E,
                                                     int* __restrict__ counts,
                                                     int* __restrict__ rank,
                                                     int nbE,
                                                     const float* __restrict__ x,
                                                     const ushort* __restrict__ W1t,
                                                     ushort* __restrict__ t1, int n){
  __shared__ ushort Abuf[64][72];
  __shared__ ushort Bbuf[128][72];
  int b = blockIdx.x;
  if (b < nbE){
    int e = b * 256 + threadIdx.x;
    if (e < E) rank[e] = atomicAdd(&counts[dst[e]], 1);
    return;
  }
  gemm_body<CIN, false, false, true>(b - nbE, x, W1t, nullptr, t1, n, Abuf, Bbuf);
}

// plain gemm (gemm2: mu/ls via blockIdx.y)
template<int K, bool IN_BF16, bool BIAS, bool OUT_BF16>
__global__ void __launch_bounds__(256) k_gemm_mfma(const void* __restrict__ Ain,
                                                   const ushort* __restrict__ Wta,
                                                   const ushort* __restrict__ Wtb,
                                                   const float* __restrict__ ba,
                                                   const float* __restrict__ bb,
                                                   void* __restrict__ outa,
                                                   void* __restrict__ outb,
                                                   int n){
  __shared__ ushort Abuf[64][72];
  __shared__ ushort Bbuf[128][72];
  const ushort* Wt   = (blockIdx.y == 0) ? Wta : Wtb;
  const float*  bias = (blockIdx.y == 0) ? ba  : bb;
  void*         outv = (blockIdx.y == 0) ? outa : outb;
  gemm_body<K, IN_BF16, BIAS, OUT_BF16>(blockIdx.x, Ain, Wt, bias, outv, n, Abuf, Bbuf);
}

// ---------------- Aggregation (ushort CSR, unscaled bf16 table) ------------
// acc_i = sum_{j in N(i)} dinv_j*table[j] + dinv_i*table[i]   (self in quarter 0)
// RELU=1: out = bf16( relu(dinv_i*acc + bias) )   (unscaled h -> next table)
// RELU=0: out = bf16( dinv_i*acc )                (g for gemm2)
// Quarter-wave (16 lanes x uint4 = 256B) per edge row; 4 edges/iter, unroll 2.

template<int RELU>
__global__ void __launch_bounds__(256) k_agg(const ushort* __restrict__ in,
                                             const float* __restrict__ bias,
                                             const int* __restrict__ rowoff,
                                             const ushort* __restrict__ csr2,
                                             const float* __restrict__ dinv,
                                             ushort* __restrict__ out, int n){
  int gid  = blockIdx.x*blockDim.x + threadIdx.x;
  int node = gid >> 6;
  int lane = gid & 63;
  if (node >= n) return;
  const int w  = lane >> 4;
  const int q  = lane & 15;
  const int f0 = q * 8;

  float acc[8] = {0,0,0,0,0,0,0,0};

  const int e0 = rowoff[node], e1 = rowoff[node+1];
  #pragma unroll 2
  for (int e = e0 + w; e < e1; e += 4){
    int s = (int)csr2[e];
    float wv = dinv[s];
    uint4 v = *(const uint4*)(in + ((size_t)s << 7) + f0);
    acc[0] = fmaf(bflo(v.x), wv, acc[0]);
    acc[1] = fmaf(bfhi(v.x), wv, acc[1]);
    acc[2] = fmaf(bflo(v.y), wv, acc[2]);
    acc[3] = fmaf(bfhi(v.y), wv, acc[3]);
    acc[4] = fmaf(bflo(v.z), wv, acc[4]);
    acc[5] = fmaf(bfhi(v.z), wv, acc[5]);
    acc[6] = fmaf(bflo(v.w), wv, acc[6]);
    acc[7] = fmaf(bfhi(v.w), wv, acc[7]);
  }
  if (w == 0){   // self term: dinv_i * table[i]
    float di = dinv[node];
    uint4 v = *(const uint4*)(in + ((size_t)node << 7) + f0);
    acc[0] = fmaf(bflo(v.x), di, acc[0]);
    acc[1] = fmaf(bfhi(v.x), di, acc[1]);
    acc[2] = fmaf(bflo(v.y), di, acc[2]);
    acc[3] = fmaf(bfhi(v.y), di, acc[3]);
    acc[4] = fmaf(bflo(v.z), di, acc[4]);
    acc[5] = fmaf(bfhi(v.z), di, acc[5]);
    acc[6] = fmaf(bflo(v.w), di, acc[6]);
    acc[7] = fmaf(bfhi(v.w), di, acc[7]);
  }
  #pragma unroll
  for (int j = 0; j < 8; j++){
    acc[j] += __shfl_xor(acc[j], 16);
    acc[j] += __shfl_xor(acc[j], 32);
  }

  if (w == 0){
    float di = dinv[node];
    uint4 p;
    if (RELU){
      float4 b0 = *(const float4*)&bias[f0];
      float4 b1 = *(const float4*)&bias[f0 + 4];
      float r0 = fmaxf(fmaf(acc[0], di, b0.x), 0.f);
      float r1 = fmaxf(fmaf(acc[1], di, b0.y), 0.f);
      float r2 = fmaxf(fmaf(acc[2], di, b0.z), 0.f);
      float r3 = fmaxf(fmaf(acc[3], di, b0.w), 0.f);
      float r4 = fmaxf(fmaf(acc[4], di, b1.x), 0.f);
      float r5 = fmaxf(fmaf(acc[5], di, b1.y), 0.f);
      float r6 = fmaxf(fmaf(acc[6], di, b1.z), 0.f);
      float r7 = fmaxf(fmaf(acc[7], di, b1.w), 0.f);
      p.x = f2bf(r0) | (f2bf(r1) << 16);
      p.y = f2bf(r2) | (f2bf(r3) << 16);
      p.z = f2bf(r4) | (f2bf(r5) << 16);
      p.w = f2bf(r6) | (f2bf(r7) << 16);
    } else {
      p.x = f2bf(acc[0] * di) | (f2bf(acc[1] * di) << 16);
      p.y = f2bf(acc[2] * di) | (f2bf(acc[3] * di) << 16);
      p.z = f2bf(acc[4] * di) | (f2bf(acc[5] * di) << 16);
      p.w = f2bf(acc[6] * di) | (f2bf(acc[7] * di) << 16);
    }
    *(uint4*)(out + ((size_t)node << 7) + f0) = p;
  }
}

// ---------------- launch ----------------

extern "C" void kernel_launch(void* const* d_in, const int* in_sizes, int n_in,
                              void* d_out, int out_size, void* d_ws, size_t ws_size,
                              hipStream_t stream){
  const float* x   = (const float*)d_in[0];
  const int*   ei  = (const int*)  d_in[1];
  const float* W1  = (const float*)d_in[2];
  const float* b1  = (const float*)d_in[3];
  const float* Wmu = (const float*)d_in[4];
  const float* bmu = (const float*)d_in[5];
  const float* Wls = (const float*)d_in[6];
  const float* bls = (const float*)d_in[7];
  int N = in_sizes[0] / CIN;
  int E = in_sizes[1] / 2;
  const int* src = ei;
  const int* dst = ei + E;
  float* out = (float*)d_out;

  char* w = (char*)d_ws;
  auto alloc = [&](size_t bytes)->char*{
    char* p = w; w += (bytes + 255) & ~(size_t)255; return p;
  };
  ushort* t1    = (ushort*)alloc((size_t)N*HFEAT*2);  // bf16 x@W1 (unscaled table 1)
  ushort* t2    = (ushort*)alloc((size_t)N*HFEAT*2);  // bf16 h   (unscaled table 2)
  ushort* gb    = (ushort*)alloc((size_t)N*HFEAT*2);  // bf16 g   (gemm2 input)
  ushort* W1bt  = (ushort*)alloc((size_t)HFEAT*CIN*2);  // bf16 W1^T  [128][256]
  ushort* Wmut  = (ushort*)alloc((size_t)HFEAT*HFEAT*2);// bf16 Wmu^T [128][128]
  ushort* Wlst  = (ushort*)alloc((size_t)HFEAT*HFEAT*2);// bf16 Wls^T [128][128]
  int*   counts = (int*)   alloc((size_t)N*4);
  float* dinv   = (float*) alloc((size_t)N*4);
  int*   rowoff = (int*)   alloc(((size_t)N+1)*4);
  int*   rank   = (int*)   alloc((size_t)E*4);
  int*   bsum   = (int*)   alloc(1024*4);
  ushort* csr2  = (ushort*)alloc((size_t)E*2);

  int nbE  = (E + 255) / 256;
  int nbS  = (N + 1023) / 1024;
  int nbG  = (N + 63) / 64;

  hipMemsetAsync(counts, 0, (size_t)N*4, stream);
  k_cvt_all <<<384, 256, 0, stream>>>(W1, Wmu, Wls, W1bt, Wmut, Wlst);
  // fused: count (+rank) || gemm1
  k_count_gemm1<<<nbE + nbG, 256, 0, stream>>>(dst, E, counts, rank, nbE,
                                               x, W1bt, t1, N);
  k_scan1   <<<nbS, 1024, 0, stream>>>(counts, N, rowoff, bsum, dinv);
  k_scan2   <<<1, 1024, 0, stream>>>(bsum, nbS);
  k_scan3   <<<nbS, 1024, 0, stream>>>(bsum, N, E, rowoff);
  k_fill    <<<nbE, 256, 0, stream>>>(src, dst, rank, E, rowoff, csr2);

  int aggBlocks = (int)(((size_t)N*64 + 255) / 256);
  // agg1: t2 = relu(dinv_i*(sum dinv_s*t1[s] + dinv_i*t1[i]) + b1)
  k_agg<1><<<aggBlocks, 256, 0, stream>>>(t1, b1, rowoff, csr2, dinv, t2, N);
  // agg2: gb = dinv_i*(sum dinv_s*t2[s] + dinv_i*t2[i])
  k_agg<0><<<aggBlocks, 256, 0, stream>>>(t2, nullptr, rowoff, csr2, dinv, gb, N);
  // gemm2: out = gb @ {Wmu,Wls} + {bmu,bls}, fp32
  k_gemm_mfma<HFEAT, true, true, false><<<dim3(nbG, 2), 256, 0, stream>>>(
      gb, Wmut, Wlst, bmu, bls, out, out + (size_t)N*HFEAT, N);
}

// Round 11
// 243.239 us; speedup vs baseline: 20.2148x; 1.0405x over previous
//
#include <hip/hip_runtime.h>
#include <hip/hip_bf16.h>
#include <cstdint>

#define HFEAT 128
#define CIN   256

typedef unsigned int  uint;
typedef unsigned short ushort;
typedef short bf16x8 __attribute__((ext_vector_type(8)));
typedef float f32x4  __attribute__((ext_vector_type(4)));

__device__ inline float bflo(uint u){ return __uint_as_float(u << 16); }
__device__ inline float bfhi(uint u){ return __uint_as_float(u & 0xffff0000u); }
__device__ inline uint  f2bf(float f){
  union { __hip_bfloat16 b; ushort u; } cvt;
  cvt.b = __float2bfloat16(f);   // RNE
  return (uint)cvt.u;
}

// ---------------- CSR build (rank-trick: atomics only in count) ----------------

// scan1 + dinv: per-1024-block inclusive scan of counts; dinv[i]=rsqrt(cnt+1)
__global__ void k_scan1(const int* __restrict__ counts, int n,
                        int* __restrict__ excl, int* __restrict__ bsum,
                        float* __restrict__ dinv){
  __shared__ int sm[1024];
  int t = threadIdx.x;
  int i = blockIdx.x*1024 + t;
  int v = (i < n) ? counts[i] : 0;
  if (i < n) dinv[i] = rsqrtf((float)v + 1.0f);
  sm[t] = v;
  __syncthreads();
  for (int off = 1; off < 1024; off <<= 1){
    int add = (t >= off) ? sm[t-off] : 0;
    __syncthreads();
    sm[t] += add;
    __syncthreads();
  }
  if (i < n) excl[i] = sm[t] - v;
  if (t == 1023) bsum[blockIdx.x] = sm[t];
}

// parallel block-sum scan (nb <= 1024)
__global__ void k_scan2(int* __restrict__ bsum, int nb){
  __shared__ int sm[1024];
  int t = threadIdx.x;
  int v = (t < nb) ? bsum[t] : 0;
  sm[t] = v;
  __syncthreads();
  for (int off = 1; off < 1024; off <<= 1){
    int add = (t >= off) ? sm[t-off] : 0;
    __syncthreads();
    sm[t] += add;
    __syncthreads();
  }
  if (t < nb) bsum[t] = sm[t] - v;   // exclusive
}

__global__ void k_scan3(const int* __restrict__ bsum, int n, int E,
                        int* __restrict__ rowoff){
  int i = blockIdx.x*blockDim.x + threadIdx.x;   // blockDim == 1024
  if (i < n) rowoff[i] += bsum[blockIdx.x];
  if (i == 0) rowoff[n] = E;
}

// no-atomic fill: pos = rowoff[dst] + rank (rank captured in count phase).
// csr entries are ushort (requires N < 65536; here N=50000).
__global__ void k_fill(const int* __restrict__ src, const int* __restrict__ dst,
                       const ushort* __restrict__ rank, int E,
                       const int* __restrict__ rowoff, ushort* __restrict__ csr2){
  int e = blockIdx.x*blockDim.x + threadIdx.x;
  if (e < E) csr2[rowoff[dst[e]] + (int)rank[e]] = (ushort)src[e];
}

// -------- all three W fp32 [K][128] -> bf16 TRANSPOSED [128][K], one kernel --------

__global__ void k_cvt_all(const float* __restrict__ W1,  const float* __restrict__ Wmu,
                          const float* __restrict__ Wls, ushort* __restrict__ W1t,
                          ushort* __restrict__ Wmut, ushort* __restrict__ Wlst){
  int b = blockIdx.x, t = threadIdx.x;            // 384 blocks x 256 threads
  if (b < 128){
    W1t[b * CIN + t] = (ushort)f2bf(W1[(size_t)t * HFEAT + b]);
  } else if (b < 256){
    int nn = b - 128;
    if (t < HFEAT) Wmut[nn * HFEAT + t] = (ushort)f2bf(Wmu[(size_t)t * HFEAT + nn]);
  } else {
    int nn = b - 256;
    if (t < HFEAT) Wlst[nn * HFEAT + t] = (ushort)f2bf(Wls[(size_t)t * HFEAT + nn]);
  }
}

// ---------------- bf16-MFMA GEMM body (device fn) ----------------
// out[N,128] = A[N,K] @ W (W pre-transposed bf16 [128][K]).
// 64x128 tile / 256-thread block (4 waves). C/D layout per guide m89:
// col=lane&15, row=(lane>>4)*4+reg.

template<int K, bool IN_BF16, bool BIAS, bool OUT_BF16>
__device__ __forceinline__ void gemm_body(int bid,
                                          const void* __restrict__ Ain,
                                          const ushort* __restrict__ Wt,
                                          const float* __restrict__ bias,
                                          void* __restrict__ outv,
                                          int n,
                                          ushort (*Abuf)[72], ushort (*Bbuf)[72]){
  const int tid  = threadIdx.x;
  const int w    = tid >> 6;
  const int l    = tid & 63;
  const int l15  = l & 15;
  const int lhi  = l >> 4;          // 0..3
  const int row0 = bid * 64;

  const int ar = tid >> 2;          // 0..63
  const int aq = tid & 3;           // 0..3
  int arow = row0 + ar; if (arow >= n) arow = n - 1;

  f32x4 acc[8];
  #pragma unroll
  for (int t = 0; t < 8; t++) acc[t] = (f32x4){0.f, 0.f, 0.f, 0.f};

  const int NT = K / 64;
  #pragma unroll
  for (int kt = 0; kt < NT; ++kt){
    if (IN_BF16){
      const ushort* ap = (const ushort*)Ain + (size_t)arow * K + aq * 16 + kt * 64;
      uint4 v0 = *(const uint4*)(ap);
      uint4 v1 = *(const uint4*)(ap + 8);
      *(uint4*)&Abuf[ar][aq * 16]     = v0;
      *(uint4*)&Abuf[ar][aq * 16 + 8] = v1;
    } else {
      const float* p = (const float*)Ain + (size_t)arow * K + aq * 16 + kt * 64;
      float4 v0 = *(const float4*)(p);
      float4 v1 = *(const float4*)(p + 4);
      float4 v2 = *(const float4*)(p + 8);
      float4 v3 = *(const float4*)(p + 12);
      uint4 pa, pb;
      pa.x = f2bf(v0.x) | (f2bf(v0.y) << 16);
      pa.y = f2bf(v0.z) | (f2bf(v0.w) << 16);
      pa.z = f2bf(v1.x) | (f2bf(v1.y) << 16);
      pa.w = f2bf(v1.z) | (f2bf(v1.w) << 16);
      pb.x = f2bf(v2.x) | (f2bf(v2.y) << 16);
      pb.y = f2bf(v2.z) | (f2bf(v2.w) << 16);
      pb.z = f2bf(v3.x) | (f2bf(v3.y) << 16);
      pb.w = f2bf(v3.z) | (f2bf(v3.w) << 16);
      *(uint4*)&Abuf[ar][aq * 16]     = pa;
      *(uint4*)&Abuf[ar][aq * 16 + 8] = pb;
    }
    #pragma unroll
    for (int j = 0; j < 4; ++j){
      int flat = tid + 256 * j;          // 0..1023
      int bn = flat >> 3;
      int bk = (flat & 7) * 8;
      uint4 v = *(const uint4*)(Wt + (size_t)bn * K + kt * 64 + bk);
      *(uint4*)&Bbuf[bn][bk] = v;
    }
    __syncthreads();

    #pragma unroll
    for (int ks = 0; ks < 2; ++ks){
      const int ko = ks * 32 + lhi * 8;
      bf16x8 af = *(bf16x8*)&Abuf[16 * w + l15][ko];
      #pragma unroll
      for (int nt = 0; nt < 8; ++nt){
        bf16x8 bf = *(bf16x8*)&Bbuf[nt * 16 + l15][ko];
        acc[nt] = __builtin_amdgcn_mfma_f32_16x16x32_bf16(af, bf, acc[nt], 0, 0, 0);
      }
    }
    __syncthreads();
  }

  float bv[8];
  #pragma unroll
  for (int nt = 0; nt < 8; ++nt) bv[nt] = BIAS ? bias[nt * 16 + l15] : 0.f;

  #pragma unroll
  for (int j = 0; j < 4; ++j){
    int r = row0 + 16 * w + lhi * 4 + j;
    if (r < n){
      if (OUT_BF16){
        ushort* orow = (ushort*)outv + (size_t)r * HFEAT + l15;
        #pragma unroll
        for (int nt = 0; nt < 8; ++nt)
          orow[nt * 16] = (ushort)f2bf(acc[nt][j] + bv[nt]);
      } else {
        float* orow = (float*)outv + (size_t)r * HFEAT + l15;
        #pragma unroll
        for (int nt = 0; nt < 8; ++nt)
          orow[nt * 16] = acc[nt][j] + bv[nt];
      }
    }
  }
}

// ---------------- fused: gemm1 || edge-count (+rank capture) ----------------
// r10 lesson: count blocks were blockIdx 0..nbE-1 -> they filled the CUs first,
// atomics ran with NOTHING to overlap, gemm started only in the tail (all pipes
// <3% busy). Fix: GEMM blocks FIRST (long-running CU residents), count blocks
// stream through the remaining slots with atomic latency hidden under MFMA.

__global__ void __launch_bounds__(256) k_count_gemm1(const int* __restrict__ dst, int E,
                                                     int* __restrict__ counts,
                                                     ushort* __restrict__ rank,
                                                     int nbG,
                                                     const float* __restrict__ x,
                                                     const ushort* __restrict__ W1t,
                                                     ushort* __restrict__ t1, int n){
  __shared__ ushort Abuf[64][72];
  __shared__ ushort Bbuf[128][72];
  int b = blockIdx.x;
  if (b >= nbG){
    int e = (b - nbG) * 256 + threadIdx.x;
    if (e < E) rank[e] = (ushort)atomicAdd(&counts[dst[e]], 1);
    return;
  }
  gemm_body<CIN, false, false, true>(b, x, W1t, nullptr, t1, n, Abuf, Bbuf);
}

// plain gemm (gemm2: mu/ls via blockIdx.y)
template<int K, bool IN_BF16, bool BIAS, bool OUT_BF16>
__global__ void __launch_bounds__(256) k_gemm_mfma(const void* __restrict__ Ain,
                                                   const ushort* __restrict__ Wta,
                                                   const ushort* __restrict__ Wtb,
                                                   const float* __restrict__ ba,
                                                   const float* __restrict__ bb,
                                                   void* __restrict__ outa,
                                                   void* __restrict__ outb,
                                                   int n){
  __shared__ ushort Abuf[64][72];
  __shared__ ushort Bbuf[128][72];
  const ushort* Wt   = (blockIdx.y == 0) ? Wta : Wtb;
  const float*  bias = (blockIdx.y == 0) ? ba  : bb;
  void*         outv = (blockIdx.y == 0) ? outa : outb;
  gemm_body<K, IN_BF16, BIAS, OUT_BF16>(blockIdx.x, Ain, Wt, bias, outv, n, Abuf, Bbuf);
}

// ---------------- Aggregation (ushort CSR, unscaled bf16 table) ------------
// acc_i = sum_{j in N(i)} dinv_j*table[j] + dinv_i*table[i]   (self in quarter 0)
// RELU=1: out = bf16( relu(dinv_i*acc + bias) )   (unscaled h -> next table)
// RELU=0: out = bf16( dinv_i*acc )                (g for gemm2)
// Quarter-wave (16 lanes x uint4 = 256B) per edge row; 4 edges/iter, unroll 2.

template<int RELU>
__global__ void __launch_bounds__(256) k_agg(const ushort* __restrict__ in,
                                             const float* __restrict__ bias,
                                             const int* __restrict__ rowoff,
                                             const ushort* __restrict__ csr2,
                                             const float* __restrict__ dinv,
                                             ushort* __restrict__ out, int n){
  int gid  = blockIdx.x*blockDim.x + threadIdx.x;
  int node = gid >> 6;
  int lane = gid & 63;
  if (node >= n) return;
  const int w  = lane >> 4;
  const int q  = lane & 15;
  const int f0 = q * 8;

  float acc[8] = {0,0,0,0,0,0,0,0};

  const int e0 = rowoff[node], e1 = rowoff[node+1];
  #pragma unroll 2
  for (int e = e0 + w; e < e1; e += 4){
    int s = (int)csr2[e];
    float wv = dinv[s];
    uint4 v = *(const uint4*)(in + ((size_t)s << 7) + f0);
    acc[0] = fmaf(bflo(v.x), wv, acc[0]);
    acc[1] = fmaf(bfhi(v.x), wv, acc[1]);
    acc[2] = fmaf(bflo(v.y), wv, acc[2]);
    acc[3] = fmaf(bfhi(v.y), wv, acc[3]);
    acc[4] = fmaf(bflo(v.z), wv, acc[4]);
    acc[5] = fmaf(bfhi(v.z), wv, acc[5]);
    acc[6] = fmaf(bflo(v.w), wv, acc[6]);
    acc[7] = fmaf(bfhi(v.w), wv, acc[7]);
  }
  if (w == 0){   // self term: dinv_i * table[i]
    float di = dinv[node];
    uint4 v = *(const uint4*)(in + ((size_t)node << 7) + f0);
    acc[0] = fmaf(bflo(v.x), di, acc[0]);
    acc[1] = fmaf(bfhi(v.x), di, acc[1]);
    acc[2] = fmaf(bflo(v.y), di, acc[2]);
    acc[3] = fmaf(bfhi(v.y), di, acc[3]);
    acc[4] = fmaf(bflo(v.z), di, acc[4]);
    acc[5] = fmaf(bfhi(v.z), di, acc[5]);
    acc[6] = fmaf(bflo(v.w), di, acc[6]);
    acc[7] = fmaf(bfhi(v.w), di, acc[7]);
  }
  #pragma unroll
  for (int j = 0; j < 8; j++){
    acc[j] += __shfl_xor(acc[j], 16);
    acc[j] += __shfl_xor(acc[j], 32);
  }

  if (w == 0){
    float di = dinv[node];
    uint4 p;
    if (RELU){
      float4 b0 = *(const float4*)&bias[f0];
      float4 b1 = *(const float4*)&bias[f0 + 4];
      float r0 = fmaxf(fmaf(acc[0], di, b0.x), 0.f);
      float r1 = fmaxf(fmaf(acc[1], di, b0.y), 0.f);
      float r2 = fmaxf(fmaf(acc[2], di, b0.z), 0.f);
      float r3 = fmaxf(fmaf(acc[3], di, b0.w), 0.f);
      float r4 = fmaxf(fmaf(acc[4], di, b1.x), 0.f);
      float r5 = fmaxf(fmaf(acc[5], di, b1.y), 0.f);
      float r6 = fmaxf(fmaf(acc[6], di, b1.z), 0.f);
      float r7 = fmaxf(fmaf(acc[7], di, b1.w), 0.f);
      p.x = f2bf(r0) | (f2bf(r1) << 16);
      p.y = f2bf(r2) | (f2bf(r3) << 16);
      p.z = f2bf(r4) | (f2bf(r5) << 16);
      p.w = f2bf(r6) | (f2bf(r7) << 16);
    } else {
      p.x = f2bf(acc[0] * di) | (f2bf(acc[1] * di) << 16);
      p.y = f2bf(acc[2] * di) | (f2bf(acc[3] * di) << 16);
      p.z = f2bf(acc[4] * di) | (f2bf(acc[5] * di) << 16);
      p.w = f2bf(acc[6] * di) | (f2bf(acc[7] * di) << 16);
    }
    *(uint4*)(out + ((size_t)node << 7) + f0) = p;
  }
}

// ---------------- launch ----------------

extern "C" void kernel_launch(void* const* d_in, const int* in_sizes, int n_in,
                              void* d_out, int out_size, void* d_ws, size_t ws_size,
                              hipStream_t stream){
  const float* x   = (const float*)d_in[0];
  const int*   ei  = (const int*)  d_in[1];
  const float* W1  = (const float*)d_in[2];
  const float* b1  = (const float*)d_in[3];
  const float* Wmu = (const float*)d_in[4];
  const float* bmu = (const float*)d_in[5];
  const float* Wls = (const float*)d_in[6];
  const float* bls = (const float*)d_in[7];
  int N = in_sizes[0] / CIN;
  int E = in_sizes[1] / 2;
  const int* src = ei;
  const int* dst = ei + E;
  float* out = (float*)d_out;

  char* w = (char*)d_ws;
  auto alloc = [&](size_t bytes)->char*{
    char* p = w; w += (bytes + 255) & ~(size_t)255; return p;
  };
  ushort* t1    = (ushort*)alloc((size_t)N*HFEAT*2);  // bf16 x@W1 (unscaled table 1)
  ushort* t2    = (ushort*)alloc((size_t)N*HFEAT*2);  // bf16 h   (unscaled table 2)
  ushort* gb    = (ushort*)alloc((size_t)N*HFEAT*2);  // bf16 g   (gemm2 input)
  ushort* W1bt  = (ushort*)alloc((size_t)HFEAT*CIN*2);  // bf16 W1^T  [128][256]
  ushort* Wmut  = (ushort*)alloc((size_t)HFEAT*HFEAT*2);// bf16 Wmu^T [128][128]
  ushort* Wlst  = (ushort*)alloc((size_t)HFEAT*HFEAT*2);// bf16 Wls^T [128][128]
  int*   counts = (int*)   alloc((size_t)N*4);
  float* dinv   = (float*) alloc((size_t)N*4);
  int*   rowoff = (int*)   alloc(((size_t)N+1)*4);
  ushort* rank  = (ushort*)alloc((size_t)E*2);
  int*   bsum   = (int*)   alloc(1024*4);
  ushort* csr2  = (ushort*)alloc((size_t)E*2);

  int nbE  = (E + 255) / 256;
  int nbS  = (N + 1023) / 1024;
  int nbG  = (N + 63) / 64;

  hipMemsetAsync(counts, 0, (size_t)N*4, stream);
  k_cvt_all <<<384, 256, 0, stream>>>(W1, Wmu, Wls, W1bt, Wmut, Wlst);
  // fused: gemm1 (blocks 0..nbG-1, CU residents) || count+rank (blocks nbG..)
  k_count_gemm1<<<nbG + nbE, 256, 0, stream>>>(dst, E, counts, rank, nbG,
                                               x, W1bt, t1, N);
  k_scan1   <<<nbS, 1024, 0, stream>>>(counts, N, rowoff, bsum, dinv);
  k_scan2   <<<1, 1024, 0, stream>>>(bsum, nbS);
  k_scan3   <<<nbS, 1024, 0, stream>>>(bsum, N, E, rowoff);
  k_fill    <<<nbE, 256, 0, stream>>>(src, dst, rank, E, rowoff, csr2);

  int aggBlocks = (int)(((size_t)N*64 + 255) / 256);
  // agg1: t2 = relu(dinv_i*(sum dinv_s*t1[s] + dinv_i*t1[i]) + b1)
  k_agg<1><<<aggBlocks, 256, 0, stream>>>(t1, b1, rowoff, csr2, dinv, t2, N);
  // agg2: gb = dinv_i*(sum dinv_s*t2[s] + dinv_i*t2[i])
  k_agg<0><<<aggBlocks, 256, 0, stream>>>(t2, nullptr, rowoff, csr2, dinv, gb, N);
  // gemm2: out = gb @ {Wmu,Wls} + {bmu,bls}, fp32
  k_gemm_mfma<HFEAT, true, true, false><<<dim3(nbG, 2), 256, 0, stream>>>(
      gb, Wmut, Wlst, bmu, bls, out, out + (size_t)N*HFEAT, N);
}